// Round 7
// baseline (422.129 us; speedup 1.0000x reference)
//
#include <hip/hip_runtime.h>

#define BB 2
#define NN 8192
#define KK 16
#define QPB 64
#define PRE 256          // prefix candidates sampled per 1024-slice (8 -> 2048 sample)
#define CAP 16           // buffered survivors per (query, subslice)
typedef unsigned long long ull;
typedef unsigned short ushort;
#define KINF 0xFFFFFFFFFFFFFFFFULL

typedef __attribute__((ext_vector_type(8))) short short8;
typedef __attribute__((ext_vector_type(4))) float f32x4;

static __device__ __forceinline__ ushort f2bf(float f) {
    unsigned u = __float_as_uint(f);
    unsigned r = (u + 0x7FFFu + ((u >> 16) & 1u)) >> 16;
    return (ushort)r;
}
static __device__ __forceinline__ float bf2f(ushort s) {
    return __uint_as_float(((unsigned)s) << 16);
}

// ---------------------------------------------------------------- prep
__global__ __launch_bounds__(256) void prep_kernel(
    const float* __restrict__ x, float4* __restrict__ pts4)
{
    int t = blockIdx.x * 256 + threadIdx.x;
    if (t < BB * NN) {
        int b = t >> 13, n = t & (NN - 1);
        float x0 = x[(b * 3 + 0) * NN + n];
        float x1 = x[(b * 3 + 1) * NN + n];
        float x2 = x[(b * 3 + 2) * NN + n];
        // same fmaf chain as the knn dot so that d(self) == 0 bit-exactly
        float sq = fmaf(x2, x2, fmaf(x1, x1, __fmul_rn(x0, x0)));
        pts4[t] = make_float4(x0, x1, x2, sq);
    }
}

// ---------------------------------------------------------------- knn K1: prefix -> conservative per-query threshold (float)
// wave w keeps a sorted TOP-4 of the first PRE candidates of slice w
// (predicated 12-inst insert, no deferral). Merge 8x4=32, pop 16 -> thr.
// thr = 16th of a subset of the sample >= 16th of sample >= true d16:
// conservative by construction; only survivor count is affected.
__global__ __launch_bounds__(512) void knn_prefix_kernel(
    const float4* __restrict__ pts4, float* __restrict__ thrb)
{
    __shared__ float smem[8 * 4 * 64];   // [wave][rank][query], 8 KB

    const int t    = threadIdx.x;
    const int wv   = t >> 6;
    const int lane = t & 63;
    const int b    = blockIdx.y;
    const int q    = blockIdx.x * QPB + lane;
    const int sl   = __builtin_amdgcn_readfirstlane(wv);

    const float4 qp = pts4[b * NN + q];
    const float4* __restrict__ cp = pts4 + (size_t)b * NN + (size_t)sl * 1024;

    float l0 = 3.0e38f, l1 = 3.0e38f, l2 = 3.0e38f, l3 = 3.0e38f;

    for (int i0 = 0; i0 < PRE; i0 += 8) {
#pragma unroll
        for (int u = 0; u < 8; ++u) {
            float4 c = cp[i0 + u];
            float dot = fmaf(qp.z, c.z, fmaf(qp.y, c.y, __fmul_rn(qp.x, c.x)));
            float d = __fadd_rn(__fsub_rn(qp.w, __fmul_rn(2.0f, dot)), c.w);
            if (d < l3) {
                bool b2 = d < l2, b1 = d < l1, b0 = d < l0;
                l3 = b2 ? l2 : d;
                l2 = b2 ? (b1 ? l1 : d) : l2;
                l1 = b1 ? (b0 ? l0 : d) : l1;
                l0 = b0 ? d : l0;
            }
        }
    }

    smem[(wv * 4 + 0) * 64 + lane] = l0;
    smem[(wv * 4 + 1) * 64 + lane] = l1;
    smem[(wv * 4 + 2) * 64 + lane] = l2;
    smem[(wv * 4 + 3) * 64 + lane] = l3;
    __syncthreads();

    if (t < QPB) {
        float h[8];
        int kc[8];
#pragma unroll
        for (int s = 0; s < 8; ++s) { h[s] = smem[(s * 4) * 64 + t]; kc[s] = 0; }
        float best = 3.0e38f;
        for (int o = 0; o < KK; ++o) {
            best = h[0]; int bs = 0;
#pragma unroll
            for (int s = 1; s < 8; ++s) { if (h[s] < best) { best = h[s]; bs = s; } }
#pragma unroll
            for (int s = 0; s < 8; ++s) {
                if (s == bs) {
                    kc[s]++;
                    h[s] = (kc[s] < 4) ? smem[(s * 4 + kc[s]) * 64 + t] : 3.0e38f;
                }
            }
        }
        thrb[(size_t)b * NN + blockIdx.x * QPB + t] = best;   // 16th of 32-subset
    }
}

// ---------------------------------------------------------------- knn K2: full scan vs float threshold
__global__ __launch_bounds__(512) void knn_scan_kernel(
    const float4* __restrict__ pts4, const float* __restrict__ thrb,
    ushort* __restrict__ buf, ushort* __restrict__ cnt)
{
    const int t    = threadIdx.x;
    const int wv   = t >> 6;
    const int lane = t & 63;
    const int b    = blockIdx.y;
    const int q    = blockIdx.x * QPB + lane;          // within batch
    const int s    = __builtin_amdgcn_readfirstlane(blockIdx.z * 8 + wv);

    const float4 qp = pts4[b * NN + q];
    const float thr = thrb[(size_t)b * NN + q];
    const float4* __restrict__ cp = pts4 + (size_t)b * NN + (size_t)s * 512;
    const unsigned cbase = s * 512;

    const int cell = (((int)(b * NN) + q) << 4) + s;   // (global q)*16 + subslice
    ushort* __restrict__ bp = buf + (size_t)cell * CAP;
    int pend = 0;

    for (int i0 = 0; i0 < 512; i0 += 8) {
#pragma unroll
        for (int u = 0; u < 8; ++u) {
            const int ci = i0 + u;
            float4 c = cp[ci];
            float dot = fmaf(qp.z, c.z, fmaf(qp.y, c.y, __fmul_rn(qp.x, c.x)));
            float d = __fadd_rn(__fsub_rn(qp.w, __fmul_rn(2.0f, dot)), c.w);
            if (d <= thr) {
                if (pend < CAP) bp[pend] = (ushort)(cbase + ci);
                pend++;
            }
        }
    }
    cnt[cell] = (ushort)((pend < CAP) ? pend : CAP);
}

// ---------------------------------------------------------------- knn K3: exact select of survivors
__global__ __launch_bounds__(256) void knn_select_kernel(
    const float4* __restrict__ pts4, const ushort* __restrict__ buf,
    const ushort* __restrict__ cnt, int* __restrict__ iout)
{
    __shared__ ull sm3[4][4][16][KK];   // 32 KB

    const int t = threadIdx.x;
    const int wv = t >> 6, lane = t & 63;
    const int qq = lane & 15, hh = lane >> 4;
    const int q  = (blockIdx.x * 4 + wv) * 16 + qq;    // global query 0..16383
    const int b  = q >> 13;

    const float4 qp = pts4[q];
    ull list[KK];
#pragma unroll
    for (int i = 0; i < KK; ++i) list[i] = KINF;

#pragma unroll
    for (int ss = 0; ss < 4; ++ss) {
        const int s = hh * 4 + ss;
        const int cell = (q << 4) + s;
        const int n = cnt[cell];
        const ushort* bp = buf + (size_t)cell * CAP;
        for (int i = 0; i < n; ++i) {
            int id = bp[i];
            float4 c = pts4[b * NN + id];
            float dot = fmaf(qp.z, c.z, fmaf(qp.y, c.y, __fmul_rn(qp.x, c.x)));
            float d = __fadd_rn(__fsub_rn(qp.w, __fmul_rn(2.0f, dot)), c.w);
            unsigned ud = __float_as_uint(d);
            ud ^= ((unsigned)((int)ud >> 31)) | 0x80000000u;
            ull k = ((ull)ud << 32) | (unsigned)id;
#pragma unroll
            for (int i2 = KK - 1; i2 > 0; --i2) {
                bool c1 = k < list[i2];
                bool c2 = k < list[i2 - 1];
                ull nd = c2 ? list[i2 - 1] : k;
                list[i2] = c1 ? nd : list[i2];
            }
            list[0] = (k < list[0]) ? k : list[0];
        }
    }

#pragma unroll
    for (int k = 0; k < KK; ++k) sm3[wv][hh][qq][k] = list[k];

    if (hh == 0) {
        ull h[4]; int kc[4];
#pragma unroll
        for (int s = 0; s < 4; ++s) { h[s] = sm3[wv][s][qq][0]; kc[s] = 0; }
        int* op = iout + (size_t)q * KK;
        for (int o = 0; o < KK; ++o) {
            ull best = h[0]; int bs = 0;
#pragma unroll
            for (int s = 1; s < 4; ++s) { if (h[s] < best) { best = h[s]; bs = s; } }
            op[o] = (int)(unsigned)(best & 0xFFFFFFFFULL);
#pragma unroll
            for (int s = 0; s < 4; ++s) {
                if (s == bs) {
                    kc[s]++;
                    h[s] = (kc[s] < KK) ? sm3[wv][s][qq][kc[s]] : KINF;
                }
            }
        }
    }
}

// ---------------------------------------------------------------- f1 (bf16 output)
__global__ __launch_bounds__(128) void f1_kernel(
    const float* __restrict__ x,
    const float* __restrict__ w1, const float* __restrict__ b1,
    const float* __restrict__ w2, const float* __restrict__ b2,
    ushort* __restrict__ f1)
{
    int P = blockIdx.x * 128 + threadIdx.x;
    if (P >= BB * NN) return;
    int b = P >> 13, n = P & (NN - 1);
    float x0 = x[(b * 3 + 0) * NN + n];
    float x1 = x[(b * 3 + 1) * NN + n];
    float x2 = x[(b * 3 + 2) * NN + n];
    float h[32];
#pragma unroll
    for (int o = 0; o < 32; ++o) {
        float v = fmaf(w1[o * 3 + 2], x2, fmaf(w1[o * 3 + 1], x1, fmaf(w1[o * 3 + 0], x0, b1[o])));
        h[o] = fmaxf(v, 0.f);
    }
#pragma unroll
    for (int o4 = 0; o4 < 16; ++o4) {
        float vv[4];
#pragma unroll
        for (int u = 0; u < 4; ++u) {
            int o = o4 * 4 + u;
            float v = b2[o];
#pragma unroll
            for (int k = 0; k < 32; ++k) v = fmaf(w2[o * 32 + k], h[k], v);
            vv[u] = fmaxf(v, 0.f);
        }
        ushort4 s = { f2bf(vv[0]), f2bf(vv[1]), f2bf(vv[2]), f2bf(vv[3]) };
        *(ushort4*)(f1 + (size_t)P * 64 + o4 * 4) = s;
    }
}

// ---------------------------------------------------------------- attention (bf16 MFMA) — layout verified round 4
// f1 is bf16 (2 MB -> per-XCD-L2-resident); 1024 blocks x 4 pts/wave for TLP
__global__ __launch_bounds__(256, 4) void attn_kernel(
    const ushort* __restrict__ f1, const int* __restrict__ idx,
    const float* __restrict__ aw1, const float* __restrict__ ab1,
    const float* __restrict__ aw2, const float* __restrict__ ab2,
    ushort* __restrict__ fagg)
{
    __shared__ __align__(16) ushort fkb[4][16][72];    // stride 144 B
    __shared__ __align__(16) ushort hb[4][16][136];    // stride 272 B

    const int t = threadIdx.x;
    const int wv = t >> 6, lane = t & 63;
    const int l15 = lane & 15, qd = lane >> 4;

    short8 w1f[8][2];
#pragma unroll
    for (int tile = 0; tile < 8; ++tile)
#pragma unroll
        for (int ks = 0; ks < 2; ++ks) {
            const float4* p = (const float4*)(aw1 + ((tile * 16 + l15) * 64 + ks * 32 + qd * 8));
            float4 A = p[0], B = p[1];
            short8 f;
            f[0] = f2bf(A.x); f[1] = f2bf(A.y); f[2] = f2bf(A.z); f[3] = f2bf(A.w);
            f[4] = f2bf(B.x); f[5] = f2bf(B.y); f[6] = f2bf(B.z); f[7] = f2bf(B.w);
            w1f[tile][ks] = f;
        }
    short8 w2f[4][4];
#pragma unroll
    for (int tile = 0; tile < 4; ++tile)
#pragma unroll
        for (int ks = 0; ks < 4; ++ks) {
            const float4* p = (const float4*)(aw2 + ((tile * 16 + l15) * 128 + ks * 32 + qd * 8));
            float4 A = p[0], B = p[1];
            short8 f;
            f[0] = f2bf(A.x); f[1] = f2bf(A.y); f[2] = f2bf(A.z); f[3] = f2bf(A.w);
            f[4] = f2bf(B.x); f[5] = f2bf(B.y); f[6] = f2bf(B.z); f[7] = f2bf(B.w);
            w2f[tile][ks] = f;
        }

    const int W = blockIdx.x * 4 + wv;
    for (int g = 0; g < 4; ++g) {
        const int P = W * 4 + g;
        const int b = P >> 13;

        float fc = bf2f(f1[(size_t)P * 64 + lane]);
        ushort fn[15];
#pragma unroll
        for (int j = 0; j < 15; ++j) {
            int nb = idx[(size_t)P * KK + 1 + j];
            fn[j] = f1[((size_t)b * NN + nb) * 64 + lane];
        }
#pragma unroll
        for (int j = 0; j < 15; ++j) fkb[wv][j][lane] = f2bf(bf2f(fn[j]) - fc);
        fkb[wv][15][lane] = 0;

        short8 a0 = *(const short8*)&fkb[wv][l15][qd * 8];
        short8 a1 = *(const short8*)&fkb[wv][l15][32 + qd * 8];

#pragma unroll
        for (int tile = 0; tile < 8; ++tile) {
            float bv = ab1[tile * 16 + l15];
            f32x4 acc = { bv, bv, bv, bv };
            acc = __builtin_amdgcn_mfma_f32_16x16x32_bf16(a0, w1f[tile][0], acc, 0, 0, 0);
            acc = __builtin_amdgcn_mfma_f32_16x16x32_bf16(a1, w1f[tile][1], acc, 0, 0, 0);
#pragma unroll
            for (int reg = 0; reg < 4; ++reg)
                hb[wv][qd * 4 + reg][tile * 16 + l15] = f2bf(fmaxf(acc[reg], 0.f));
        }

        short8 a2[4];
#pragma unroll
        for (int ks = 0; ks < 4; ++ks)
            a2[ks] = *(const short8*)&hb[wv][l15][ks * 32 + qd * 8];

        f32x4 L[4];
#pragma unroll
        for (int tile = 0; tile < 4; ++tile) {
            float bv = ab2[tile * 16 + l15];
            f32x4 acc = { bv, bv, bv, bv };
#pragma unroll
            for (int ks = 0; ks < 4; ++ks)
                acc = __builtin_amdgcn_mfma_f32_16x16x32_bf16(a2[ks], w2f[tile][ks], acc, 0, 0, 0);
            L[tile] = acc;
        }

        float fa[4];
#pragma unroll
        for (int tile = 0; tile < 4; ++tile) {
            float m1 = -3.0e38f;
#pragma unroll
            for (int reg = 0; reg < 4; ++reg)
                if (qd * 4 + reg < 15) m1 = fmaxf(m1, L[tile][reg]);
            m1 = fmaxf(m1, __shfl_xor(m1, 16));
            m1 = fmaxf(m1, __shfl_xor(m1, 32));
            float e[4], ssum = 0.f;
#pragma unroll
            for (int reg = 0; reg < 4; ++reg) {
                bool valid = (qd * 4 + reg < 15);
                e[reg] = valid ? __expf(L[tile][reg] - m1) : 0.f;
                ssum += e[reg];
            }
            ssum += __shfl_xor(ssum, 16);
            ssum += __shfl_xor(ssum, 32);
            float part = 0.f;
#pragma unroll
            for (int reg = 0; reg < 4; ++reg) {
                float fkv = bf2f(fkb[wv][qd * 4 + reg][tile * 16 + l15]);
                part = fmaf(e[reg], fkv, part);
            }
            part += __shfl_xor(part, 16);
            part += __shfl_xor(part, 32);
            fa[tile] = part / ssum;
        }
        if (qd == 0) {
#pragma unroll
            for (int tile = 0; tile < 4; ++tile)
                fagg[(size_t)P * 64 + tile * 16 + l15] = f2bf(fa[tile]);
        }
    }
}

// ---------------------------------------------------------------- cov + mlp2 (bf16 output)
__global__ __launch_bounds__(128) void cov_kernel(
    const float4* __restrict__ pts4, const int* __restrict__ idx,
    const float* __restrict__ w, const float* __restrict__ bb,
    ushort* __restrict__ fcov)
{
    int P = blockIdx.x * 128 + threadIdx.x;
    if (P >= BB * NN) return;
    int b = P >> 13;
    const int4* ip4 = (const int4*)(idx + (size_t)P * KK);
    int ids[KK];
#pragma unroll
    for (int g = 0; g < 4; ++g) {
        int4 v = ip4[g];
        ids[g * 4 + 0] = v.x; ids[g * 4 + 1] = v.y;
        ids[g * 4 + 2] = v.z; ids[g * 4 + 3] = v.w;
    }
    float px[KK], py[KK], pz[KK];
#pragma unroll
    for (int k = 0; k < KK; ++k) {
        float4 c = pts4[b * NN + ids[k]];
        px[k] = c.x; py[k] = c.y; pz[k] = c.z;
    }
    float mx = 0.f, my = 0.f, mz = 0.f;
#pragma unroll
    for (int k = 0; k < KK; ++k) { mx += px[k]; my += py[k]; mz += pz[k]; }
    mx *= (1.f / 16.f); my *= (1.f / 16.f); mz *= (1.f / 16.f);
    float c00 = 0, c01 = 0, c02 = 0, c11 = 0, c12 = 0, c22 = 0;
#pragma unroll
    for (int k = 0; k < KK; ++k) {
        float dx = px[k] - mx, dy = py[k] - my, dz = pz[k] - mz;
        c00 = fmaf(dx, dx, c00); c01 = fmaf(dx, dy, c01); c02 = fmaf(dx, dz, c02);
        c11 = fmaf(dy, dy, c11); c12 = fmaf(dy, dz, c12); c22 = fmaf(dz, dz, c22);
    }
    const float inv = 1.f / 16.f;
    float cf[9] = { c00 * inv, c01 * inv, c02 * inv,
                    c01 * inv, c11 * inv, c12 * inv,
                    c02 * inv, c12 * inv, c22 * inv };
    ushort* out = fcov + (size_t)P * 32;
#pragma unroll
    for (int o = 0; o < 32; ++o) {
        float v = bb[o];
#pragma unroll
        for (int m = 0; m < 9; ++m) v = fmaf(w[o * 9 + m], cf[m], v);
        out[o] = f2bf(fmaxf(v, 0.f));
    }
}

// ---------------------------------------------------------------- mlp3 + output (bf16 MFMA) — verified round 6
__global__ __launch_bounds__(256) void mlp3_kernel(
    const ushort* __restrict__ fagg, const ushort* __restrict__ fcov,
    const float* __restrict__ w1, const float* __restrict__ b1,
    const float* __restrict__ w2, const float* __restrict__ b2,
    const float* __restrict__ x, float* __restrict__ out)
{
    __shared__ __align__(16) ushort fb[4][16][104];    // 13.3 KB
    __shared__ __align__(16) ushort hb[4][16][136];    // 17.4 KB

    const int t = threadIdx.x;
    const int wv = t >> 6, lane = t & 63;
    const int l15 = lane & 15, qd = lane >> 4;

    short8 w1f[8][3];
#pragma unroll
    for (int tile = 0; tile < 8; ++tile)
#pragma unroll
        for (int ks = 0; ks < 3; ++ks) {
            const float* p = w1 + ((size_t)(tile * 16 + l15) * 96 + ks * 32 + qd * 8);
            float4 A = *(const float4*)p, B = *(const float4*)(p + 4);
            short8 f;
            f[0] = f2bf(A.x); f[1] = f2bf(A.y); f[2] = f2bf(A.z); f[3] = f2bf(A.w);
            f[4] = f2bf(B.x); f[5] = f2bf(B.y); f[6] = f2bf(B.z); f[7] = f2bf(B.w);
            w1f[tile][ks] = f;
        }
    short8 w2f[4];
#pragma unroll
    for (int ks = 0; ks < 4; ++ks) {
        short8 f = {};
        if (l15 < 12) {
            const float* p = w2 + ((size_t)l15 * 128 + ks * 32 + qd * 8);
            float4 A = *(const float4*)p, B = *(const float4*)(p + 4);
            f[0] = f2bf(A.x); f[1] = f2bf(A.y); f[2] = f2bf(A.z); f[3] = f2bf(A.w);
            f[4] = f2bf(B.x); f[5] = f2bf(B.y); f[6] = f2bf(B.z); f[7] = f2bf(B.w);
        }
        w2f[ks] = f;
    }

    const int T = blockIdx.x * 4 + wv;    // tile 0..1023

    // ---- stage f = [fagg | fcov] (already bf16) into A-layout
    {
        const int pt = lane >> 2, c4 = lane & 3;
        const ushort* fap = fagg + ((size_t)(T * 16 + pt) * 64 + c4 * 16);
        *(short8*)&fb[wv][pt][c4 * 16]     = *(const short8*)(fap);
        *(short8*)&fb[wv][pt][c4 * 16 + 8] = *(const short8*)(fap + 8);
        const ushort* fcp = fcov + ((size_t)(T * 16 + pt) * 32 + c4 * 8);
        *(short8*)&fb[wv][pt][64 + c4 * 8] = *(const short8*)(fcp);
    }

    short8 a[3];
#pragma unroll
    for (int ks = 0; ks < 3; ++ks)
        a[ks] = *(const short8*)&fb[wv][l15][ks * 32 + qd * 8];

#pragma unroll
    for (int tile = 0; tile < 8; ++tile) {
        float bv = b1[tile * 16 + l15];
        f32x4 acc = { bv, bv, bv, bv };
#pragma unroll
        for (int ks = 0; ks < 3; ++ks)
            acc = __builtin_amdgcn_mfma_f32_16x16x32_bf16(a[ks], w1f[tile][ks], acc, 0, 0, 0);
#pragma unroll
        for (int reg = 0; reg < 4; ++reg)
            hb[wv][qd * 4 + reg][tile * 16 + l15] = f2bf(fmaxf(acc[reg], 0.f));
    }

    short8 a2[4];
#pragma unroll
    for (int ks = 0; ks < 4; ++ks)
        a2[ks] = *(const short8*)&hb[wv][l15][ks * 32 + qd * 8];

    float bv2 = (l15 < 12) ? b2[l15] : 0.f;
    f32x4 acc = { bv2, bv2, bv2, bv2 };
#pragma unroll
    for (int ks = 0; ks < 4; ++ks)
        acc = __builtin_amdgcn_mfma_f32_16x16x32_bf16(a2[ks], w2f[ks], acc, 0, 0, 0);

    if (l15 < 12) {
        const int c = l15 >> 2, rr = l15 & 3;
#pragma unroll
        for (int reg = 0; reg < 4; ++reg) {
            int P = T * 16 + qd * 4 + reg;
            int b = P >> 13, n = P & (NN - 1);
            float xv = x[((size_t)b * 3 + c) * NN + n];
            out[(((size_t)b * 3 + c) * 4 + rr) * NN + n] = xv + 0.15f * acc[reg];
        }
    }
}

// ---------------------------------------------------------------- launch
extern "C" void kernel_launch(void* const* d_in, const int* in_sizes, int n_in,
                              void* d_out, int out_size, void* d_ws, size_t ws_size,
                              hipStream_t stream)
{
    (void)in_sizes; (void)n_in; (void)out_size; (void)ws_size;
    const float* x    = (const float*)d_in[0];
    const float* m1w1 = (const float*)d_in[1];
    const float* m1b1 = (const float*)d_in[2];
    const float* m1w2 = (const float*)d_in[3];
    const float* m1b2 = (const float*)d_in[4];
    const float* m2w1 = (const float*)d_in[5];
    const float* m2b1 = (const float*)d_in[6];
    const float* m3w1 = (const float*)d_in[7];
    const float* m3b1 = (const float*)d_in[8];
    const float* m3w2 = (const float*)d_in[9];
    const float* m3b2 = (const float*)d_in[10];
    const float* aw1  = (const float*)d_in[11];
    const float* ab1  = (const float*)d_in[12];
    const float* aw2  = (const float*)d_in[13];
    const float* ab2  = (const float*)d_in[14];
    float* out = (float*)d_out;

    char* ws = (char*)d_ws;
    float4* pts4 = (float4*)(ws + 0);             //   262144 B
    float*  thrb = (float*)(ws + 262144);         //    65536 B
    int*    idxb = (int*)  (ws + 327680);         //  1048576 B
    ushort* cntb = (ushort*)(ws + 1376256);       //   524288 B
    ushort* bufb = (ushort*)(ws + 1900544);       //  8388608 B
    ushort* f1b  = (ushort*)(ws + 10289152);      //  2097152 B
    ushort* fagg = (ushort*)(ws + 12386304);      //  2097152 B
    ushort* fcov = (ushort*)(ws + 14483456);      //  1048576 B

    prep_kernel<<<64, 256, 0, stream>>>(x, pts4);
    knn_prefix_kernel<<<dim3(NN / QPB, BB), 512, 0, stream>>>(pts4, thrb);
    knn_scan_kernel<<<dim3(NN / QPB, BB, 2), 512, 0, stream>>>(pts4, thrb, bufb, cntb);
    knn_select_kernel<<<256, 256, 0, stream>>>(pts4, bufb, cntb, idxb);
    f1_kernel<<<128, 128, 0, stream>>>(x, m1w1, m1b1, m1w2, m1b2, f1b);
    attn_kernel<<<1024, 256, 0, stream>>>(f1b, idxb, aw1, ab1, aw2, ab2, fagg);
    cov_kernel<<<128, 128, 0, stream>>>(pts4, idxb, m2w1, m2b1, fcov);
    mlp3_kernel<<<256, 256, 0, stream>>>(fagg, fcov, m3w1, m3b1, m3w2, m3b2, x, out);
}

// Round 8
// 333.105 us; speedup vs baseline: 1.2673x; 1.2673x over previous
//
#include <hip/hip_runtime.h>

#define BB 2
#define NN 8192
#define KK 16
#define QPB 64
#define PRE 256          // prefix candidates sampled per 1024-slice (8 -> 2048 sample)
#define CAP 16           // buffered survivors per (query, subslice)
typedef unsigned long long ull;
typedef unsigned short ushort;
#define KINF 0xFFFFFFFFFFFFFFFFULL

typedef __attribute__((ext_vector_type(8))) short short8;
typedef __attribute__((ext_vector_type(4))) float f32x4;

static __device__ __forceinline__ ushort f2bf(float f) {
    unsigned u = __float_as_uint(f);
    unsigned r = (u + 0x7FFFu + ((u >> 16) & 1u)) >> 16;
    return (ushort)r;
}
static __device__ __forceinline__ float bf2f(ushort s) {
    return __uint_as_float(((unsigned)s) << 16);
}

// ---------------------------------------------------------------- prep
__global__ __launch_bounds__(256) void prep_kernel(
    const float* __restrict__ x, float4* __restrict__ pts4)
{
    int t = blockIdx.x * 256 + threadIdx.x;
    if (t < BB * NN) {
        int b = t >> 13, n = t & (NN - 1);
        float x0 = x[(b * 3 + 0) * NN + n];
        float x1 = x[(b * 3 + 1) * NN + n];
        float x2 = x[(b * 3 + 2) * NN + n];
        // same fmaf chain as the knn dot so that d(self) == 0 bit-exactly
        float sq = fmaf(x2, x2, fmaf(x1, x1, __fmul_rn(x0, x0)));
        pts4[t] = make_float4(x0, x1, x2, sq);
    }
}

// ---------------------------------------------------------------- knn K1: prefix -> conservative per-query threshold (float)
// wave w keeps a sorted TOP-4 of the first PRE candidates of slice w
// (predicated insert). Merge 8x4=32, pop 16 -> thr (conservative >= true d16).
__global__ __launch_bounds__(512) void knn_prefix_kernel(
    const float4* __restrict__ pts4, float* __restrict__ thrb)
{
    __shared__ float smem[8 * 4 * 64];   // [wave][rank][query], 8 KB

    const int t    = threadIdx.x;
    const int wv   = t >> 6;
    const int lane = t & 63;
    const int b    = blockIdx.y;
    const int q    = blockIdx.x * QPB + lane;
    const int sl   = __builtin_amdgcn_readfirstlane(wv);

    const float4 qp = pts4[b * NN + q];
    const float4* __restrict__ cp = pts4 + (size_t)b * NN + (size_t)sl * 1024;

    float l0 = 3.0e38f, l1 = 3.0e38f, l2 = 3.0e38f, l3 = 3.0e38f;

    for (int i0 = 0; i0 < PRE; i0 += 8) {
#pragma unroll
        for (int u = 0; u < 8; ++u) {
            float4 c = cp[i0 + u];
            float dot = fmaf(qp.z, c.z, fmaf(qp.y, c.y, __fmul_rn(qp.x, c.x)));
            float d = __fadd_rn(__fsub_rn(qp.w, __fmul_rn(2.0f, dot)), c.w);
            if (d < l3) {
                bool b2 = d < l2, b1 = d < l1, b0 = d < l0;
                l3 = b2 ? l2 : d;
                l2 = b2 ? (b1 ? l1 : d) : l2;
                l1 = b1 ? (b0 ? l0 : d) : l1;
                l0 = b0 ? d : l0;
            }
        }
    }

    smem[(wv * 4 + 0) * 64 + lane] = l0;
    smem[(wv * 4 + 1) * 64 + lane] = l1;
    smem[(wv * 4 + 2) * 64 + lane] = l2;
    smem[(wv * 4 + 3) * 64 + lane] = l3;
    __syncthreads();

    if (t < QPB) {
        float h[8];
        int kc[8];
#pragma unroll
        for (int s = 0; s < 8; ++s) { h[s] = smem[(s * 4) * 64 + t]; kc[s] = 0; }
        float best = 3.0e38f;
        for (int o = 0; o < KK; ++o) {
            best = h[0]; int bs = 0;
#pragma unroll
            for (int s = 1; s < 8; ++s) { if (h[s] < best) { best = h[s]; bs = s; } }
#pragma unroll
            for (int s = 0; s < 8; ++s) {
                if (s == bs) {
                    kc[s]++;
                    h[s] = (kc[s] < 4) ? smem[(s * 4 + kc[s]) * 64 + t] : 3.0e38f;
                }
            }
        }
        thrb[(size_t)b * NN + blockIdx.x * QPB + t] = best;   // 16th of 32-subset
    }
}

// ---------------------------------------------------------------- knn K2: full scan vs float threshold
__global__ __launch_bounds__(512) void knn_scan_kernel(
    const float4* __restrict__ pts4, const float* __restrict__ thrb,
    ushort* __restrict__ buf, ushort* __restrict__ cnt)
{
    const int t    = threadIdx.x;
    const int wv   = t >> 6;
    const int lane = t & 63;
    const int b    = blockIdx.y;
    const int q    = blockIdx.x * QPB + lane;          // within batch
    const int s    = __builtin_amdgcn_readfirstlane(blockIdx.z * 8 + wv);

    const float4 qp = pts4[b * NN + q];
    const float thr = thrb[(size_t)b * NN + q];
    const float4* __restrict__ cp = pts4 + (size_t)b * NN + (size_t)s * 512;
    const unsigned cbase = s * 512;

    const int cell = (((int)(b * NN) + q) << 4) + s;   // (global q)*16 + subslice
    ushort* __restrict__ bp = buf + (size_t)cell * CAP;
    int pend = 0;

    for (int i0 = 0; i0 < 512; i0 += 8) {
#pragma unroll
        for (int u = 0; u < 8; ++u) {
            const int ci = i0 + u;
            float4 c = cp[ci];
            float dot = fmaf(qp.z, c.z, fmaf(qp.y, c.y, __fmul_rn(qp.x, c.x)));
            float d = __fadd_rn(__fsub_rn(qp.w, __fmul_rn(2.0f, dot)), c.w);
            if (d <= thr) {
                if (pend < CAP) bp[pend] = (ushort)(cbase + ci);
                pend++;
            }
        }
    }
    cnt[cell] = (ushort)((pend < CAP) ? pend : CAP);
}

// ---------------------------------------------------------------- knn K3: exact select of survivors
__global__ __launch_bounds__(256) void knn_select_kernel(
    const float4* __restrict__ pts4, const ushort* __restrict__ buf,
    const ushort* __restrict__ cnt, int* __restrict__ iout)
{
    __shared__ ull sm3[4][4][16][KK];   // 32 KB

    const int t = threadIdx.x;
    const int wv = t >> 6, lane = t & 63;
    const int qq = lane & 15, hh = lane >> 4;
    const int q  = (blockIdx.x * 4 + wv) * 16 + qq;    // global query 0..16383
    const int b  = q >> 13;

    const float4 qp = pts4[q];
    ull list[KK];
#pragma unroll
    for (int i = 0; i < KK; ++i) list[i] = KINF;

#pragma unroll
    for (int ss = 0; ss < 4; ++ss) {
        const int s = hh * 4 + ss;
        const int cell = (q << 4) + s;
        const int n = cnt[cell];
        const ushort* bp = buf + (size_t)cell * CAP;
        for (int i = 0; i < n; ++i) {
            int id = bp[i];
            float4 c = pts4[b * NN + id];
            float dot = fmaf(qp.z, c.z, fmaf(qp.y, c.y, __fmul_rn(qp.x, c.x)));
            float d = __fadd_rn(__fsub_rn(qp.w, __fmul_rn(2.0f, dot)), c.w);
            unsigned ud = __float_as_uint(d);
            ud ^= ((unsigned)((int)ud >> 31)) | 0x80000000u;
            ull k = ((ull)ud << 32) | (unsigned)id;
#pragma unroll
            for (int i2 = KK - 1; i2 > 0; --i2) {
                bool c1 = k < list[i2];
                bool c2 = k < list[i2 - 1];
                ull nd = c2 ? list[i2 - 1] : k;
                list[i2] = c1 ? nd : list[i2];
            }
            list[0] = (k < list[0]) ? k : list[0];
        }
    }

#pragma unroll
    for (int k = 0; k < KK; ++k) sm3[wv][hh][qq][k] = list[k];

    if (hh == 0) {
        ull h[4]; int kc[4];
#pragma unroll
        for (int s = 0; s < 4; ++s) { h[s] = sm3[wv][s][qq][0]; kc[s] = 0; }
        int* op = iout + (size_t)q * KK;
        for (int o = 0; o < KK; ++o) {
            ull best = h[0]; int bs = 0;
#pragma unroll
            for (int s = 1; s < 4; ++s) { if (h[s] < best) { best = h[s]; bs = s; } }
            op[o] = (int)(unsigned)(best & 0xFFFFFFFFULL);
#pragma unroll
            for (int s = 0; s < 4; ++s) {
                if (s == bs) {
                    kc[s]++;
                    h[s] = (kc[s] < KK) ? sm3[wv][s][qq][kc[s]] : KINF;
                }
            }
        }
    }
}

// ---------------------------------------------------------------- f1 (bf16 output)
__global__ __launch_bounds__(128) void f1_kernel(
    const float* __restrict__ x,
    const float* __restrict__ w1, const float* __restrict__ b1,
    const float* __restrict__ w2, const float* __restrict__ b2,
    ushort* __restrict__ f1)
{
    int P = blockIdx.x * 128 + threadIdx.x;
    if (P >= BB * NN) return;
    int b = P >> 13, n = P & (NN - 1);
    float x0 = x[(b * 3 + 0) * NN + n];
    float x1 = x[(b * 3 + 1) * NN + n];
    float x2 = x[(b * 3 + 2) * NN + n];
    float h[32];
#pragma unroll
    for (int o = 0; o < 32; ++o) {
        float v = fmaf(w1[o * 3 + 2], x2, fmaf(w1[o * 3 + 1], x1, fmaf(w1[o * 3 + 0], x0, b1[o])));
        h[o] = fmaxf(v, 0.f);
    }
#pragma unroll
    for (int o4 = 0; o4 < 16; ++o4) {
        float vv[4];
#pragma unroll
        for (int u = 0; u < 4; ++u) {
            int o = o4 * 4 + u;
            float v = b2[o];
#pragma unroll
            for (int k = 0; k < 32; ++k) v = fmaf(w2[o * 32 + k], h[k], v);
            vv[u] = fmaxf(v, 0.f);
        }
        ushort4 s = { f2bf(vv[0]), f2bf(vv[1]), f2bf(vv[2]), f2bf(vv[3]) };
        *(ushort4*)(f1 + (size_t)P * 64 + o4 * 4) = s;
    }
}

// ---------------------------------------------------------------- attention (bf16 MFMA) — layout verified round 4
// f1 is bf16 (2 MB -> per-XCD-L2-resident). __launch_bounds__(256,2): the
// (256,4) variant capped VGPRs at 64 and spilled the 128-VGPR weight frags
// to scratch (280 MB FETCH / 242 MB WRITE, 180 us — round 7). Keep 2.
__global__ __launch_bounds__(256, 2) void attn_kernel(
    const ushort* __restrict__ f1, const int* __restrict__ idx,
    const float* __restrict__ aw1, const float* __restrict__ ab1,
    const float* __restrict__ aw2, const float* __restrict__ ab2,
    ushort* __restrict__ fagg)
{
    __shared__ __align__(16) ushort fkb[4][16][72];    // stride 144 B
    __shared__ __align__(16) ushort hb[4][16][136];    // stride 272 B

    const int t = threadIdx.x;
    const int wv = t >> 6, lane = t & 63;
    const int l15 = lane & 15, qd = lane >> 4;

    short8 w1f[8][2];
#pragma unroll
    for (int tile = 0; tile < 8; ++tile)
#pragma unroll
        for (int ks = 0; ks < 2; ++ks) {
            const float4* p = (const float4*)(aw1 + ((tile * 16 + l15) * 64 + ks * 32 + qd * 8));
            float4 A = p[0], B = p[1];
            short8 f;
            f[0] = f2bf(A.x); f[1] = f2bf(A.y); f[2] = f2bf(A.z); f[3] = f2bf(A.w);
            f[4] = f2bf(B.x); f[5] = f2bf(B.y); f[6] = f2bf(B.z); f[7] = f2bf(B.w);
            w1f[tile][ks] = f;
        }
    short8 w2f[4][4];
#pragma unroll
    for (int tile = 0; tile < 4; ++tile)
#pragma unroll
        for (int ks = 0; ks < 4; ++ks) {
            const float4* p = (const float4*)(aw2 + ((tile * 16 + l15) * 128 + ks * 32 + qd * 8));
            float4 A = p[0], B = p[1];
            short8 f;
            f[0] = f2bf(A.x); f[1] = f2bf(A.y); f[2] = f2bf(A.z); f[3] = f2bf(A.w);
            f[4] = f2bf(B.x); f[5] = f2bf(B.y); f[6] = f2bf(B.z); f[7] = f2bf(B.w);
            w2f[tile][ks] = f;
        }

    const int W = blockIdx.x * 4 + wv;
    for (int g = 0; g < 4; ++g) {
        const int P = W * 4 + g;
        const int b = P >> 13;

        float fc = bf2f(f1[(size_t)P * 64 + lane]);
        ushort fn[15];
#pragma unroll
        for (int j = 0; j < 15; ++j) {
            int nb = idx[(size_t)P * KK + 1 + j];
            fn[j] = f1[((size_t)b * NN + nb) * 64 + lane];
        }
#pragma unroll
        for (int j = 0; j < 15; ++j) fkb[wv][j][lane] = f2bf(bf2f(fn[j]) - fc);
        fkb[wv][15][lane] = 0;

        short8 a0 = *(const short8*)&fkb[wv][l15][qd * 8];
        short8 a1 = *(const short8*)&fkb[wv][l15][32 + qd * 8];

#pragma unroll
        for (int tile = 0; tile < 8; ++tile) {
            float bv = ab1[tile * 16 + l15];
            f32x4 acc = { bv, bv, bv, bv };
            acc = __builtin_amdgcn_mfma_f32_16x16x32_bf16(a0, w1f[tile][0], acc, 0, 0, 0);
            acc = __builtin_amdgcn_mfma_f32_16x16x32_bf16(a1, w1f[tile][1], acc, 0, 0, 0);
#pragma unroll
            for (int reg = 0; reg < 4; ++reg)
                hb[wv][qd * 4 + reg][tile * 16 + l15] = f2bf(fmaxf(acc[reg], 0.f));
        }

        short8 a2[4];
#pragma unroll
        for (int ks = 0; ks < 4; ++ks)
            a2[ks] = *(const short8*)&hb[wv][l15][ks * 32 + qd * 8];

        f32x4 L[4];
#pragma unroll
        for (int tile = 0; tile < 4; ++tile) {
            float bv = ab2[tile * 16 + l15];
            f32x4 acc = { bv, bv, bv, bv };
#pragma unroll
            for (int ks = 0; ks < 4; ++ks)
                acc = __builtin_amdgcn_mfma_f32_16x16x32_bf16(a2[ks], w2f[tile][ks], acc, 0, 0, 0);
            L[tile] = acc;
        }

        float fa[4];
#pragma unroll
        for (int tile = 0; tile < 4; ++tile) {
            float m1 = -3.0e38f;
#pragma unroll
            for (int reg = 0; reg < 4; ++reg)
                if (qd * 4 + reg < 15) m1 = fmaxf(m1, L[tile][reg]);
            m1 = fmaxf(m1, __shfl_xor(m1, 16));
            m1 = fmaxf(m1, __shfl_xor(m1, 32));
            float e[4], ssum = 0.f;
#pragma unroll
            for (int reg = 0; reg < 4; ++reg) {
                bool valid = (qd * 4 + reg < 15);
                e[reg] = valid ? __expf(L[tile][reg] - m1) : 0.f;
                ssum += e[reg];
            }
            ssum += __shfl_xor(ssum, 16);
            ssum += __shfl_xor(ssum, 32);
            float part = 0.f;
#pragma unroll
            for (int reg = 0; reg < 4; ++reg) {
                float fkv = bf2f(fkb[wv][qd * 4 + reg][tile * 16 + l15]);
                part = fmaf(e[reg], fkv, part);
            }
            part += __shfl_xor(part, 16);
            part += __shfl_xor(part, 32);
            fa[tile] = part / ssum;
        }
        if (qd == 0) {
#pragma unroll
            for (int tile = 0; tile < 4; ++tile)
                fagg[(size_t)P * 64 + tile * 16 + l15] = f2bf(fa[tile]);
        }
    }
}

// ---------------------------------------------------------------- cov + mlp2 (bf16 output)
__global__ __launch_bounds__(128) void cov_kernel(
    const float4* __restrict__ pts4, const int* __restrict__ idx,
    const float* __restrict__ w, const float* __restrict__ bb,
    ushort* __restrict__ fcov)
{
    int P = blockIdx.x * 128 + threadIdx.x;
    if (P >= BB * NN) return;
    int b = P >> 13;
    const int4* ip4 = (const int4*)(idx + (size_t)P * KK);
    int ids[KK];
#pragma unroll
    for (int g = 0; g < 4; ++g) {
        int4 v = ip4[g];
        ids[g * 4 + 0] = v.x; ids[g * 4 + 1] = v.y;
        ids[g * 4 + 2] = v.z; ids[g * 4 + 3] = v.w;
    }
    float px[KK], py[KK], pz[KK];
#pragma unroll
    for (int k = 0; k < KK; ++k) {
        float4 c = pts4[b * NN + ids[k]];
        px[k] = c.x; py[k] = c.y; pz[k] = c.z;
    }
    float mx = 0.f, my = 0.f, mz = 0.f;
#pragma unroll
    for (int k = 0; k < KK; ++k) { mx += px[k]; my += py[k]; mz += pz[k]; }
    mx *= (1.f / 16.f); my *= (1.f / 16.f); mz *= (1.f / 16.f);
    float c00 = 0, c01 = 0, c02 = 0, c11 = 0, c12 = 0, c22 = 0;
#pragma unroll
    for (int k = 0; k < KK; ++k) {
        float dx = px[k] - mx, dy = py[k] - my, dz = pz[k] - mz;
        c00 = fmaf(dx, dx, c00); c01 = fmaf(dx, dy, c01); c02 = fmaf(dx, dz, c02);
        c11 = fmaf(dy, dy, c11); c12 = fmaf(dy, dz, c12); c22 = fmaf(dz, dz, c22);
    }
    const float inv = 1.f / 16.f;
    float cf[9] = { c00 * inv, c01 * inv, c02 * inv,
                    c01 * inv, c11 * inv, c12 * inv,
                    c02 * inv, c12 * inv, c22 * inv };
    ushort* out = fcov + (size_t)P * 32;
#pragma unroll
    for (int o = 0; o < 32; ++o) {
        float v = bb[o];
#pragma unroll
        for (int m = 0; m < 9; ++m) v = fmaf(w[o * 9 + m], cf[m], v);
        out[o] = f2bf(fmaxf(v, 0.f));
    }
}

// ---------------------------------------------------------------- mlp3 + output (bf16 MFMA) — verified round 6
__global__ __launch_bounds__(256) void mlp3_kernel(
    const ushort* __restrict__ fagg, const ushort* __restrict__ fcov,
    const float* __restrict__ w1, const float* __restrict__ b1,
    const float* __restrict__ w2, const float* __restrict__ b2,
    const float* __restrict__ x, float* __restrict__ out)
{
    __shared__ __align__(16) ushort fb[4][16][104];    // 13.3 KB
    __shared__ __align__(16) ushort hb[4][16][136];    // 17.4 KB

    const int t = threadIdx.x;
    const int wv = t >> 6, lane = t & 63;
    const int l15 = lane & 15, qd = lane >> 4;

    short8 w1f[8][3];
#pragma unroll
    for (int tile = 0; tile < 8; ++tile)
#pragma unroll
        for (int ks = 0; ks < 3; ++ks) {
            const float* p = w1 + ((size_t)(tile * 16 + l15) * 96 + ks * 32 + qd * 8);
            float4 A = *(const float4*)p, B = *(const float4*)(p + 4);
            short8 f;
            f[0] = f2bf(A.x); f[1] = f2bf(A.y); f[2] = f2bf(A.z); f[3] = f2bf(A.w);
            f[4] = f2bf(B.x); f[5] = f2bf(B.y); f[6] = f2bf(B.z); f[7] = f2bf(B.w);
            w1f[tile][ks] = f;
        }
    short8 w2f[4];
#pragma unroll
    for (int ks = 0; ks < 4; ++ks) {
        short8 f = {};
        if (l15 < 12) {
            const float* p = w2 + ((size_t)l15 * 128 + ks * 32 + qd * 8);
            float4 A = *(const float4*)p, B = *(const float4*)(p + 4);
            f[0] = f2bf(A.x); f[1] = f2bf(A.y); f[2] = f2bf(A.z); f[3] = f2bf(A.w);
            f[4] = f2bf(B.x); f[5] = f2bf(B.y); f[6] = f2bf(B.z); f[7] = f2bf(B.w);
        }
        w2f[ks] = f;
    }

    const int T = blockIdx.x * 4 + wv;    // tile 0..1023

    // ---- stage f = [fagg | fcov] (already bf16) into A-layout
    {
        const int pt = lane >> 2, c4 = lane & 3;
        const ushort* fap = fagg + ((size_t)(T * 16 + pt) * 64 + c4 * 16);
        *(short8*)&fb[wv][pt][c4 * 16]     = *(const short8*)(fap);
        *(short8*)&fb[wv][pt][c4 * 16 + 8] = *(const short8*)(fap + 8);
        const ushort* fcp = fcov + ((size_t)(T * 16 + pt) * 32 + c4 * 8);
        *(short8*)&fb[wv][pt][64 + c4 * 8] = *(const short8*)(fcp);
    }

    short8 a[3];
#pragma unroll
    for (int ks = 0; ks < 3; ++ks)
        a[ks] = *(const short8*)&fb[wv][l15][ks * 32 + qd * 8];

#pragma unroll
    for (int tile = 0; tile < 8; ++tile) {
        float bv = b1[tile * 16 + l15];
        f32x4 acc = { bv, bv, bv, bv };
#pragma unroll
        for (int ks = 0; ks < 3; ++ks)
            acc = __builtin_amdgcn_mfma_f32_16x16x32_bf16(a[ks], w1f[tile][ks], acc, 0, 0, 0);
#pragma unroll
        for (int reg = 0; reg < 4; ++reg)
            hb[wv][qd * 4 + reg][tile * 16 + l15] = f2bf(fmaxf(acc[reg], 0.f));
    }

    short8 a2[4];
#pragma unroll
    for (int ks = 0; ks < 4; ++ks)
        a2[ks] = *(const short8*)&hb[wv][l15][ks * 32 + qd * 8];

    float bv2 = (l15 < 12) ? b2[l15] : 0.f;
    f32x4 acc = { bv2, bv2, bv2, bv2 };
#pragma unroll
    for (int ks = 0; ks < 4; ++ks)
        acc = __builtin_amdgcn_mfma_f32_16x16x32_bf16(a2[ks], w2f[ks], acc, 0, 0, 0);

    if (l15 < 12) {
        const int c = l15 >> 2, rr = l15 & 3;
#pragma unroll
        for (int reg = 0; reg < 4; ++reg) {
            int P = T * 16 + qd * 4 + reg;
            int b = P >> 13, n = P & (NN - 1);
            float xv = x[((size_t)b * 3 + c) * NN + n];
            out[(((size_t)b * 3 + c) * 4 + rr) * NN + n] = xv + 0.15f * acc[reg];
        }
    }
}

// ---------------------------------------------------------------- launch
extern "C" void kernel_launch(void* const* d_in, const int* in_sizes, int n_in,
                              void* d_out, int out_size, void* d_ws, size_t ws_size,
                              hipStream_t stream)
{
    (void)in_sizes; (void)n_in; (void)out_size; (void)ws_size;
    const float* x    = (const float*)d_in[0];
    const float* m1w1 = (const float*)d_in[1];
    const float* m1b1 = (const float*)d_in[2];
    const float* m1w2 = (const float*)d_in[3];
    const float* m1b2 = (const float*)d_in[4];
    const float* m2w1 = (const float*)d_in[5];
    const float* m2b1 = (const float*)d_in[6];
    const float* m3w1 = (const float*)d_in[7];
    const float* m3b1 = (const float*)d_in[8];
    const float* m3w2 = (const float*)d_in[9];
    const float* m3b2 = (const float*)d_in[10];
    const float* aw1  = (const float*)d_in[11];
    const float* ab1  = (const float*)d_in[12];
    const float* aw2  = (const float*)d_in[13];
    const float* ab2  = (const float*)d_in[14];
    float* out = (float*)d_out;

    char* ws = (char*)d_ws;
    float4* pts4 = (float4*)(ws + 0);             //   262144 B
    float*  thrb = (float*)(ws + 262144);         //    65536 B
    int*    idxb = (int*)  (ws + 327680);         //  1048576 B
    ushort* cntb = (ushort*)(ws + 1376256);       //   524288 B
    ushort* bufb = (ushort*)(ws + 1900544);       //  8388608 B
    ushort* f1b  = (ushort*)(ws + 10289152);      //  2097152 B
    ushort* fagg = (ushort*)(ws + 12386304);      //  2097152 B
    ushort* fcov = (ushort*)(ws + 14483456);      //  1048576 B

    prep_kernel<<<64, 256, 0, stream>>>(x, pts4);
    knn_prefix_kernel<<<dim3(NN / QPB, BB), 512, 0, stream>>>(pts4, thrb);
    knn_scan_kernel<<<dim3(NN / QPB, BB, 2), 512, 0, stream>>>(pts4, thrb, bufb, cntb);
    knn_select_kernel<<<256, 256, 0, stream>>>(pts4, bufb, cntb, idxb);
    f1_kernel<<<128, 128, 0, stream>>>(x, m1w1, m1b1, m1w2, m1b2, f1b);
    attn_kernel<<<1024, 256, 0, stream>>>(f1b, idxb, aw1, ab1, aw2, ab2, fagg);
    cov_kernel<<<128, 128, 0, stream>>>(pts4, idxb, m2w1, m2b1, fcov);
    mlp3_kernel<<<256, 256, 0, stream>>>(fagg, fcov, m3w1, m3b1, m3w2, m3b2, x, out);
}

// Round 9
// 333.005 us; speedup vs baseline: 1.2676x; 1.0003x over previous
//
#include <hip/hip_runtime.h>

#define BB 2
#define NN 8192
#define KK 16
#define QPB 64
#define PRE 256          // prefix candidates sampled per 1024-slice (8 -> 2048 sample)
#define CAP 16           // buffered survivors per (query, subslice)
typedef unsigned long long ull;
typedef unsigned short ushort;
#define KINF 0xFFFFFFFFFFFFFFFFULL

typedef __attribute__((ext_vector_type(8))) short short8;
typedef __attribute__((ext_vector_type(4))) float f32x4;

static __device__ __forceinline__ ushort f2bf(float f) {
    unsigned u = __float_as_uint(f);
    unsigned r = (u + 0x7FFFu + ((u >> 16) & 1u)) >> 16;
    return (ushort)r;
}
static __device__ __forceinline__ float bf2f(ushort s) {
    return __uint_as_float(((unsigned)s) << 16);
}

// ---------------------------------------------------------------- prep
__global__ __launch_bounds__(256) void prep_kernel(
    const float* __restrict__ x, float4* __restrict__ pts4)
{
    int t = blockIdx.x * 256 + threadIdx.x;
    if (t < BB * NN) {
        int b = t >> 13, n = t & (NN - 1);
        float x0 = x[(b * 3 + 0) * NN + n];
        float x1 = x[(b * 3 + 1) * NN + n];
        float x2 = x[(b * 3 + 2) * NN + n];
        // same fmaf chain as the knn dot so that d(self) == 0 bit-exactly
        float sq = fmaf(x2, x2, fmaf(x1, x1, __fmul_rn(x0, x0)));
        pts4[t] = make_float4(x0, x1, x2, sq);
    }
}

// ---------------------------------------------------------------- knn K1: prefix -> conservative per-query threshold (float)
__global__ __launch_bounds__(512) void knn_prefix_kernel(
    const float4* __restrict__ pts4, float* __restrict__ thrb)
{
    __shared__ float smem[8 * 4 * 64];   // [wave][rank][query], 8 KB

    const int t    = threadIdx.x;
    const int wv   = t >> 6;
    const int lane = t & 63;
    const int b    = blockIdx.y;
    const int q    = blockIdx.x * QPB + lane;
    const int sl   = __builtin_amdgcn_readfirstlane(wv);

    const float4 qp = pts4[b * NN + q];
    const float4* __restrict__ cp = pts4 + (size_t)b * NN + (size_t)sl * 1024;

    float l0 = 3.0e38f, l1 = 3.0e38f, l2 = 3.0e38f, l3 = 3.0e38f;

    for (int i0 = 0; i0 < PRE; i0 += 8) {
#pragma unroll
        for (int u = 0; u < 8; ++u) {
            float4 c = cp[i0 + u];
            float dot = fmaf(qp.z, c.z, fmaf(qp.y, c.y, __fmul_rn(qp.x, c.x)));
            float d = __fadd_rn(__fsub_rn(qp.w, __fmul_rn(2.0f, dot)), c.w);
            if (d < l3) {
                bool b2 = d < l2, b1 = d < l1, b0 = d < l0;
                l3 = b2 ? l2 : d;
                l2 = b2 ? (b1 ? l1 : d) : l2;
                l1 = b1 ? (b0 ? l0 : d) : l1;
                l0 = b0 ? d : l0;
            }
        }
    }

    smem[(wv * 4 + 0) * 64 + lane] = l0;
    smem[(wv * 4 + 1) * 64 + lane] = l1;
    smem[(wv * 4 + 2) * 64 + lane] = l2;
    smem[(wv * 4 + 3) * 64 + lane] = l3;
    __syncthreads();

    if (t < QPB) {
        float h[8];
        int kc[8];
#pragma unroll
        for (int s = 0; s < 8; ++s) { h[s] = smem[(s * 4) * 64 + t]; kc[s] = 0; }
        float best = 3.0e38f;
        for (int o = 0; o < KK; ++o) {
            best = h[0]; int bs = 0;
#pragma unroll
            for (int s = 1; s < 8; ++s) { if (h[s] < best) { best = h[s]; bs = s; } }
#pragma unroll
            for (int s = 0; s < 8; ++s) {
                if (s == bs) {
                    kc[s]++;
                    h[s] = (kc[s] < 4) ? smem[(s * 4 + kc[s]) * 64 + t] : 3.0e38f;
                }
            }
        }
        thrb[(size_t)b * NN + blockIdx.x * QPB + t] = best;   // 16th of 32-subset
    }
}

// ---------------------------------------------------------------- knn K2: full scan vs float threshold
__global__ __launch_bounds__(512) void knn_scan_kernel(
    const float4* __restrict__ pts4, const float* __restrict__ thrb,
    ushort* __restrict__ buf, ushort* __restrict__ cnt)
{
    const int t    = threadIdx.x;
    const int wv   = t >> 6;
    const int lane = t & 63;
    const int b    = blockIdx.y;
    const int q    = blockIdx.x * QPB + lane;          // within batch
    const int s    = __builtin_amdgcn_readfirstlane(blockIdx.z * 8 + wv);

    const float4 qp = pts4[b * NN + q];
    const float thr = thrb[(size_t)b * NN + q];
    const float4* __restrict__ cp = pts4 + (size_t)b * NN + (size_t)s * 512;
    const unsigned cbase = s * 512;

    const int cell = (((int)(b * NN) + q) << 4) + s;   // (global q)*16 + subslice
    ushort* __restrict__ bp = buf + (size_t)cell * CAP;
    int pend = 0;

    for (int i0 = 0; i0 < 512; i0 += 8) {
#pragma unroll
        for (int u = 0; u < 8; ++u) {
            const int ci = i0 + u;
            float4 c = cp[ci];
            float dot = fmaf(qp.z, c.z, fmaf(qp.y, c.y, __fmul_rn(qp.x, c.x)));
            float d = __fadd_rn(__fsub_rn(qp.w, __fmul_rn(2.0f, dot)), c.w);
            if (d <= thr) {
                if (pend < CAP) bp[pend] = (ushort)(cbase + ci);
                pend++;
            }
        }
    }
    cnt[cell] = (ushort)((pend < CAP) ? pend : CAP);
}

// ---------------------------------------------------------------- knn K3: exact select of survivors
__global__ __launch_bounds__(256) void knn_select_kernel(
    const float4* __restrict__ pts4, const ushort* __restrict__ buf,
    const ushort* __restrict__ cnt, int* __restrict__ iout)
{
    __shared__ ull sm3[4][4][16][KK];   // 32 KB

    const int t = threadIdx.x;
    const int wv = t >> 6, lane = t & 63;
    const int qq = lane & 15, hh = lane >> 4;
    const int q  = (blockIdx.x * 4 + wv) * 16 + qq;    // global query 0..16383
    const int b  = q >> 13;

    const float4 qp = pts4[q];
    ull list[KK];
#pragma unroll
    for (int i = 0; i < KK; ++i) list[i] = KINF;

#pragma unroll
    for (int ss = 0; ss < 4; ++ss) {
        const int s = hh * 4 + ss;
        const int cell = (q << 4) + s;
        const int n = cnt[cell];
        const ushort* bp = buf + (size_t)cell * CAP;
        for (int i = 0; i < n; ++i) {
            int id = bp[i];
            float4 c = pts4[b * NN + id];
            float dot = fmaf(qp.z, c.z, fmaf(qp.y, c.y, __fmul_rn(qp.x, c.x)));
            float d = __fadd_rn(__fsub_rn(qp.w, __fmul_rn(2.0f, dot)), c.w);
            unsigned ud = __float_as_uint(d);
            ud ^= ((unsigned)((int)ud >> 31)) | 0x80000000u;
            ull k = ((ull)ud << 32) | (unsigned)id;
#pragma unroll
            for (int i2 = KK - 1; i2 > 0; --i2) {
                bool c1 = k < list[i2];
                bool c2 = k < list[i2 - 1];
                ull nd = c2 ? list[i2 - 1] : k;
                list[i2] = c1 ? nd : list[i2];
            }
            list[0] = (k < list[0]) ? k : list[0];
        }
    }

#pragma unroll
    for (int k = 0; k < KK; ++k) sm3[wv][hh][qq][k] = list[k];

    if (hh == 0) {
        ull h[4]; int kc[4];
#pragma unroll
        for (int s = 0; s < 4; ++s) { h[s] = sm3[wv][s][qq][0]; kc[s] = 0; }
        int* op = iout + (size_t)q * KK;
        for (int o = 0; o < KK; ++o) {
            ull best = h[0]; int bs = 0;
#pragma unroll
            for (int s = 1; s < 4; ++s) { if (h[s] < best) { best = h[s]; bs = s; } }
            op[o] = (int)(unsigned)(best & 0xFFFFFFFFULL);
#pragma unroll
            for (int s = 0; s < 4; ++s) {
                if (s == bs) {
                    kc[s]++;
                    h[s] = (kc[s] < KK) ? sm3[wv][s][qq][kc[s]] : KINF;
                }
            }
        }
    }
}

// ---------------------------------------------------------------- f1 (bf16 output)
__global__ __launch_bounds__(128) void f1_kernel(
    const float* __restrict__ x,
    const float* __restrict__ w1, const float* __restrict__ b1,
    const float* __restrict__ w2, const float* __restrict__ b2,
    ushort* __restrict__ f1)
{
    int P = blockIdx.x * 128 + threadIdx.x;
    if (P >= BB * NN) return;
    int b = P >> 13, n = P & (NN - 1);
    float x0 = x[(b * 3 + 0) * NN + n];
    float x1 = x[(b * 3 + 1) * NN + n];
    float x2 = x[(b * 3 + 2) * NN + n];
    float h[32];
#pragma unroll
    for (int o = 0; o < 32; ++o) {
        float v = fmaf(w1[o * 3 + 2], x2, fmaf(w1[o * 3 + 1], x1, fmaf(w1[o * 3 + 0], x0, b1[o])));
        h[o] = fmaxf(v, 0.f);
    }
#pragma unroll
    for (int o4 = 0; o4 < 16; ++o4) {
        float vv[4];
#pragma unroll
        for (int u = 0; u < 4; ++u) {
            int o = o4 * 4 + u;
            float v = b2[o];
#pragma unroll
            for (int k = 0; k < 32; ++k) v = fmaf(w2[o * 32 + k], h[k], v);
            vv[u] = fmaxf(v, 0.f);
        }
        ushort4 s = { f2bf(vv[0]), f2bf(vv[1]), f2bf(vv[2]), f2bf(vv[3]) };
        *(ushort4*)(f1 + (size_t)P * 64 + o4 * 4) = s;
    }
}

// ---------------------------------------------------------------- attention A: gather + layer1 (w1 frags only -> no spill)
// Outputs: fkg[P][j][64] bf16 (j=15 row zeroed), Hg[P][j][128] bf16 = relu(L1)
__global__ __launch_bounds__(256, 2) void attn_a_kernel(
    const ushort* __restrict__ f1, const int* __restrict__ idx,
    const float* __restrict__ aw1, const float* __restrict__ ab1,
    ushort* __restrict__ Hg, ushort* __restrict__ fkg)
{
    __shared__ __align__(16) ushort fkb[4][16][72];    // per-wave, stride 144 B

    const int t = threadIdx.x;
    const int wv = t >> 6, lane = t & 63;
    const int l15 = lane & 15, qd = lane >> 4;

    short8 w1f[8][2];
#pragma unroll
    for (int tile = 0; tile < 8; ++tile)
#pragma unroll
        for (int ks = 0; ks < 2; ++ks) {
            const float4* p = (const float4*)(aw1 + ((tile * 16 + l15) * 64 + ks * 32 + qd * 8));
            float4 A = p[0], B = p[1];
            short8 f;
            f[0] = f2bf(A.x); f[1] = f2bf(A.y); f[2] = f2bf(A.z); f[3] = f2bf(A.w);
            f[4] = f2bf(B.x); f[5] = f2bf(B.y); f[6] = f2bf(B.z); f[7] = f2bf(B.w);
            w1f[tile][ks] = f;
        }

    const int W = blockIdx.x * 4 + wv;
    for (int g = 0; g < 4; ++g) {
        const int P = W * 4 + g;
        const int b = P >> 13;

        float fc = bf2f(f1[(size_t)P * 64 + lane]);
        ushort fn[15];
#pragma unroll
        for (int j = 0; j < 15; ++j) {
            int nb = idx[(size_t)P * KK + 1 + j];
            fn[j] = f1[((size_t)b * NN + nb) * 64 + lane];
        }
        ushort* fkp = fkg + (size_t)P * 1024;
#pragma unroll
        for (int j = 0; j < 15; ++j) {
            ushort v = f2bf(bf2f(fn[j]) - fc);
            fkb[wv][j][lane] = v;
            fkp[j * 64 + lane] = v;                     // coalesced 128B row
        }
        fkb[wv][15][lane] = 0;
        fkp[15 * 64 + lane] = 0;

        short8 a0 = *(const short8*)&fkb[wv][l15][qd * 8];
        short8 a1 = *(const short8*)&fkb[wv][l15][32 + qd * 8];

        ushort* hp = Hg + (size_t)P * 2048;             // [j][128]
#pragma unroll
        for (int tile = 0; tile < 8; ++tile) {
            float bv = ab1[tile * 16 + l15];
            f32x4 acc = { bv, bv, bv, bv };
            acc = __builtin_amdgcn_mfma_f32_16x16x32_bf16(a0, w1f[tile][0], acc, 0, 0, 0);
            acc = __builtin_amdgcn_mfma_f32_16x16x32_bf16(a1, w1f[tile][1], acc, 0, 0, 0);
#pragma unroll
            for (int reg = 0; reg < 4; ++reg)
                hp[(qd * 4 + reg) * 128 + tile * 16 + l15] = f2bf(fmaxf(acc[reg], 0.f));
        }
    }
}

// ---------------------------------------------------------------- attention B: layer2 + softmax + aggregate (w2 frags only)
__global__ __launch_bounds__(256, 1) void attn_b_kernel(
    const ushort* __restrict__ Hg, const ushort* __restrict__ fkg,
    const float* __restrict__ aw2, const float* __restrict__ ab2,
    ushort* __restrict__ fagg)
{
    const int t = threadIdx.x;
    const int wv = t >> 6, lane = t & 63;
    const int l15 = lane & 15, qd = lane >> 4;

    short8 w2f[4][4];
#pragma unroll
    for (int tile = 0; tile < 4; ++tile)
#pragma unroll
        for (int ks = 0; ks < 4; ++ks) {
            const float4* p = (const float4*)(aw2 + ((tile * 16 + l15) * 128 + ks * 32 + qd * 8));
            float4 A = p[0], B = p[1];
            short8 f;
            f[0] = f2bf(A.x); f[1] = f2bf(A.y); f[2] = f2bf(A.z); f[3] = f2bf(A.w);
            f[4] = f2bf(B.x); f[5] = f2bf(B.y); f[6] = f2bf(B.z); f[7] = f2bf(B.w);
            w2f[tile][ks] = f;
        }

    const int W = blockIdx.x * 4 + wv;
    for (int g = 0; g < 4; ++g) {
        const int P = W * 4 + g;

        // A-frags for layer 2 from Hg[P][j=l15][k]
        const ushort* hp = Hg + (size_t)P * 2048;
        short8 a2[4];
#pragma unroll
        for (int ks = 0; ks < 4; ++ks)
            a2[ks] = *(const short8*)(hp + l15 * 128 + ks * 32 + qd * 8);

        // fk values at C-layout positions: fk[j=qd*4+reg][c=tile*16+l15]
        const ushort* fkp = fkg + (size_t)P * 1024;
        ushort fkv[4][4];
#pragma unroll
        for (int tile = 0; tile < 4; ++tile)
#pragma unroll
            for (int reg = 0; reg < 4; ++reg)
                fkv[tile][reg] = fkp[(qd * 4 + reg) * 64 + tile * 16 + l15];

        f32x4 L[4];
#pragma unroll
        for (int tile = 0; tile < 4; ++tile) {
            float bv = ab2[tile * 16 + l15];
            f32x4 acc = { bv, bv, bv, bv };
#pragma unroll
            for (int ks = 0; ks < 4; ++ks)
                acc = __builtin_amdgcn_mfma_f32_16x16x32_bf16(a2[ks], w2f[tile][ks], acc, 0, 0, 0);
            L[tile] = acc;
        }

        float fa[4];
#pragma unroll
        for (int tile = 0; tile < 4; ++tile) {
            float m1 = -3.0e38f;
#pragma unroll
            for (int reg = 0; reg < 4; ++reg)
                if (qd * 4 + reg < 15) m1 = fmaxf(m1, L[tile][reg]);
            m1 = fmaxf(m1, __shfl_xor(m1, 16));
            m1 = fmaxf(m1, __shfl_xor(m1, 32));
            float e[4], ssum = 0.f;
#pragma unroll
            for (int reg = 0; reg < 4; ++reg) {
                bool valid = (qd * 4 + reg < 15);
                e[reg] = valid ? __expf(L[tile][reg] - m1) : 0.f;
                ssum += e[reg];
            }
            ssum += __shfl_xor(ssum, 16);
            ssum += __shfl_xor(ssum, 32);
            float part = 0.f;
#pragma unroll
            for (int reg = 0; reg < 4; ++reg)
                part = fmaf(e[reg], bf2f(fkv[tile][reg]), part);
            part += __shfl_xor(part, 16);
            part += __shfl_xor(part, 32);
            fa[tile] = part / ssum;
        }
        if (qd == 0) {
#pragma unroll
            for (int tile = 0; tile < 4; ++tile)
                fagg[(size_t)P * 64 + tile * 16 + l15] = f2bf(fa[tile]);
        }
    }
}

// ---------------------------------------------------------------- cov + mlp2 (bf16 output)
__global__ __launch_bounds__(128) void cov_kernel(
    const float4* __restrict__ pts4, const int* __restrict__ idx,
    const float* __restrict__ w, const float* __restrict__ bb,
    ushort* __restrict__ fcov)
{
    int P = blockIdx.x * 128 + threadIdx.x;
    if (P >= BB * NN) return;
    int b = P >> 13;
    const int4* ip4 = (const int4*)(idx + (size_t)P * KK);
    int ids[KK];
#pragma unroll
    for (int g = 0; g < 4; ++g) {
        int4 v = ip4[g];
        ids[g * 4 + 0] = v.x; ids[g * 4 + 1] = v.y;
        ids[g * 4 + 2] = v.z; ids[g * 4 + 3] = v.w;
    }
    float px[KK], py[KK], pz[KK];
#pragma unroll
    for (int k = 0; k < KK; ++k) {
        float4 c = pts4[b * NN + ids[k]];
        px[k] = c.x; py[k] = c.y; pz[k] = c.z;
    }
    float mx = 0.f, my = 0.f, mz = 0.f;
#pragma unroll
    for (int k = 0; k < KK; ++k) { mx += px[k]; my += py[k]; mz += pz[k]; }
    mx *= (1.f / 16.f); my *= (1.f / 16.f); mz *= (1.f / 16.f);
    float c00 = 0, c01 = 0, c02 = 0, c11 = 0, c12 = 0, c22 = 0;
#pragma unroll
    for (int k = 0; k < KK; ++k) {
        float dx = px[k] - mx, dy = py[k] - my, dz = pz[k] - mz;
        c00 = fmaf(dx, dx, c00); c01 = fmaf(dx, dy, c01); c02 = fmaf(dx, dz, c02);
        c11 = fmaf(dy, dy, c11); c12 = fmaf(dy, dz, c12); c22 = fmaf(dz, dz, c22);
    }
    const float inv = 1.f / 16.f;
    float cf[9] = { c00 * inv, c01 * inv, c02 * inv,
                    c01 * inv, c11 * inv, c12 * inv,
                    c02 * inv, c12 * inv, c22 * inv };
    ushort* out = fcov + (size_t)P * 32;
#pragma unroll
    for (int o = 0; o < 32; ++o) {
        float v = bb[o];
#pragma unroll
        for (int m = 0; m < 9; ++m) v = fmaf(w[o * 9 + m], cf[m], v);
        out[o] = f2bf(fmaxf(v, 0.f));
    }
}

// ---------------------------------------------------------------- mlp3 + output (bf16 MFMA) — verified round 6
__global__ __launch_bounds__(256) void mlp3_kernel(
    const ushort* __restrict__ fagg, const ushort* __restrict__ fcov,
    const float* __restrict__ w1, const float* __restrict__ b1,
    const float* __restrict__ w2, const float* __restrict__ b2,
    const float* __restrict__ x, float* __restrict__ out)
{
    __shared__ __align__(16) ushort fb[4][16][104];    // 13.3 KB
    __shared__ __align__(16) ushort hb[4][16][136];    // 17.4 KB

    const int t = threadIdx.x;
    const int wv = t >> 6, lane = t & 63;
    const int l15 = lane & 15, qd = lane >> 4;

    short8 w1f[8][3];
#pragma unroll
    for (int tile = 0; tile < 8; ++tile)
#pragma unroll
        for (int ks = 0; ks < 3; ++ks) {
            const float* p = w1 + ((size_t)(tile * 16 + l15) * 96 + ks * 32 + qd * 8);
            float4 A = *(const float4*)p, B = *(const float4*)(p + 4);
            short8 f;
            f[0] = f2bf(A.x); f[1] = f2bf(A.y); f[2] = f2bf(A.z); f[3] = f2bf(A.w);
            f[4] = f2bf(B.x); f[5] = f2bf(B.y); f[6] = f2bf(B.z); f[7] = f2bf(B.w);
            w1f[tile][ks] = f;
        }
    short8 w2f[4];
#pragma unroll
    for (int ks = 0; ks < 4; ++ks) {
        short8 f = {};
        if (l15 < 12) {
            const float* p = w2 + ((size_t)l15 * 128 + ks * 32 + qd * 8);
            float4 A = *(const float4*)p, B = *(const float4*)(p + 4);
            f[0] = f2bf(A.x); f[1] = f2bf(A.y); f[2] = f2bf(A.z); f[3] = f2bf(A.w);
            f[4] = f2bf(B.x); f[5] = f2bf(B.y); f[6] = f2bf(B.z); f[7] = f2bf(B.w);
        }
        w2f[ks] = f;
    }

    const int T = blockIdx.x * 4 + wv;    // tile 0..1023

    // ---- stage f = [fagg | fcov] (already bf16) into A-layout
    {
        const int pt = lane >> 2, c4 = lane & 3;
        const ushort* fap = fagg + ((size_t)(T * 16 + pt) * 64 + c4 * 16);
        *(short8*)&fb[wv][pt][c4 * 16]     = *(const short8*)(fap);
        *(short8*)&fb[wv][pt][c4 * 16 + 8] = *(const short8*)(fap + 8);
        const ushort* fcp = fcov + ((size_t)(T * 16 + pt) * 32 + c4 * 8);
        *(short8*)&fb[wv][pt][64 + c4 * 8] = *(const short8*)(fcp);
    }

    short8 a[3];
#pragma unroll
    for (int ks = 0; ks < 3; ++ks)
        a[ks] = *(const short8*)&fb[wv][l15][ks * 32 + qd * 8];

#pragma unroll
    for (int tile = 0; tile < 8; ++tile) {
        float bv = b1[tile * 16 + l15];
        f32x4 acc = { bv, bv, bv, bv };
#pragma unroll
        for (int ks = 0; ks < 3; ++ks)
            acc = __builtin_amdgcn_mfma_f32_16x16x32_bf16(a[ks], w1f[tile][ks], acc, 0, 0, 0);
#pragma unroll
        for (int reg = 0; reg < 4; ++reg)
            hb[wv][qd * 4 + reg][tile * 16 + l15] = f2bf(fmaxf(acc[reg], 0.f));
    }

    short8 a2[4];
#pragma unroll
    for (int ks = 0; ks < 4; ++ks)
        a2[ks] = *(const short8*)&hb[wv][l15][ks * 32 + qd * 8];

    float bv2 = (l15 < 12) ? b2[l15] : 0.f;
    f32x4 acc = { bv2, bv2, bv2, bv2 };
#pragma unroll
    for (int ks = 0; ks < 4; ++ks)
        acc = __builtin_amdgcn_mfma_f32_16x16x32_bf16(a2[ks], w2f[ks], acc, 0, 0, 0);

    if (l15 < 12) {
        const int c = l15 >> 2, rr = l15 & 3;
#pragma unroll
        for (int reg = 0; reg < 4; ++reg) {
            int P = T * 16 + qd * 4 + reg;
            int b = P >> 13, n = P & (NN - 1);
            float xv = x[((size_t)b * 3 + c) * NN + n];
            out[(((size_t)b * 3 + c) * 4 + rr) * NN + n] = xv + 0.15f * acc[reg];
        }
    }
}

// ---------------------------------------------------------------- launch
extern "C" void kernel_launch(void* const* d_in, const int* in_sizes, int n_in,
                              void* d_out, int out_size, void* d_ws, size_t ws_size,
                              hipStream_t stream)
{
    (void)in_sizes; (void)n_in; (void)out_size; (void)ws_size;
    const float* x    = (const float*)d_in[0];
    const float* m1w1 = (const float*)d_in[1];
    const float* m1b1 = (const float*)d_in[2];
    const float* m1w2 = (const float*)d_in[3];
    const float* m1b2 = (const float*)d_in[4];
    const float* m2w1 = (const float*)d_in[5];
    const float* m2b1 = (const float*)d_in[6];
    const float* m3w1 = (const float*)d_in[7];
    const float* m3b1 = (const float*)d_in[8];
    const float* m3w2 = (const float*)d_in[9];
    const float* m3b2 = (const float*)d_in[10];
    const float* aw1  = (const float*)d_in[11];
    const float* ab1  = (const float*)d_in[12];
    const float* aw2  = (const float*)d_in[13];
    const float* ab2  = (const float*)d_in[14];
    float* out = (float*)d_out;

    char* ws = (char*)d_ws;
    float4* pts4 = (float4*)(ws + 0);             //   262144 B
    float*  thrb = (float*)(ws + 262144);         //    65536 B
    int*    idxb = (int*)  (ws + 327680);         //  1048576 B
    ushort* cntb = (ushort*)(ws + 1376256);       //   524288 B
    ushort* bufb = (ushort*)(ws + 1900544);       //  8388608 B
    ushort* f1b  = (ushort*)(ws + 10289152);      //  2097152 B
    ushort* fagg = (ushort*)(ws + 12386304);      //  2097152 B
    ushort* fcov = (ushort*)(ws + 14483456);      //  1048576 B
    ushort* Hg   = (ushort*)(ws + 15532032);      //  4194304 B
    ushort* fkg  = (ushort*)(ws + 19726336);      //  2097152 B

    prep_kernel<<<64, 256, 0, stream>>>(x, pts4);
    knn_prefix_kernel<<<dim3(NN / QPB, BB), 512, 0, stream>>>(pts4, thrb);
    knn_scan_kernel<<<dim3(NN / QPB, BB, 2), 512, 0, stream>>>(pts4, thrb, bufb, cntb);
    knn_select_kernel<<<256, 256, 0, stream>>>(pts4, bufb, cntb, idxb);
    f1_kernel<<<128, 128, 0, stream>>>(x, m1w1, m1b1, m1w2, m1b2, f1b);
    attn_a_kernel<<<1024, 256, 0, stream>>>(f1b, idxb, aw1, ab1, Hg, fkg);
    attn_b_kernel<<<1024, 256, 0, stream>>>(Hg, fkg, aw2, ab2, fagg);
    cov_kernel<<<128, 128, 0, stream>>>(pts4, idxb, m2w1, m2b1, fcov);
    mlp3_kernel<<<256, 256, 0, stream>>>(fagg, fcov, m3w1, m3b1, m3w2, m3b2, x, out);
}

// Round 10
// 309.653 us; speedup vs baseline: 1.3632x; 1.0754x over previous
//
#include <hip/hip_runtime.h>

#define BB 2
#define NN 8192
#define KK 16
#define QPB 64
#define PRE 256          // prefix candidates sampled per 1024-slice (8 -> 2048 sample)
#define NSL 32           // K2/K3 subslices per query (256 candidates each)
#define CAP 10           // buffered survivors per (query, subslice); lambda~2.2
typedef unsigned long long ull;
typedef unsigned short ushort;
#define KINF 0xFFFFFFFFFFFFFFFFULL

typedef __attribute__((ext_vector_type(8))) short short8;
typedef __attribute__((ext_vector_type(4))) float f32x4;

static __device__ __forceinline__ ushort f2bf(float f) {
    unsigned u = __float_as_uint(f);
    unsigned r = (u + 0x7FFFu + ((u >> 16) & 1u)) >> 16;
    return (ushort)r;
}
static __device__ __forceinline__ float bf2f(ushort s) {
    return __uint_as_float(((unsigned)s) << 16);
}

// ---------------------------------------------------------------- prep
__global__ __launch_bounds__(256) void prep_kernel(
    const float* __restrict__ x, float4* __restrict__ pts4)
{
    int t = blockIdx.x * 256 + threadIdx.x;
    if (t < BB * NN) {
        int b = t >> 13, n = t & (NN - 1);
        float x0 = x[(b * 3 + 0) * NN + n];
        float x1 = x[(b * 3 + 1) * NN + n];
        float x2 = x[(b * 3 + 2) * NN + n];
        // same fmaf chain as the knn dot so that d(self) == 0 bit-exactly
        float sq = fmaf(x2, x2, fmaf(x1, x1, __fmul_rn(x0, x0)));
        pts4[t] = make_float4(x0, x1, x2, sq);
    }
}

// ---------------------------------------------------------------- knn K1: prefix -> conservative per-query threshold (float)
__global__ __launch_bounds__(512) void knn_prefix_kernel(
    const float4* __restrict__ pts4, float* __restrict__ thrb)
{
    __shared__ float smem[8 * 4 * 64];   // [wave][rank][query], 8 KB

    const int t    = threadIdx.x;
    const int wv   = t >> 6;
    const int lane = t & 63;
    const int b    = blockIdx.y;
    const int q    = blockIdx.x * QPB + lane;
    const int sl   = __builtin_amdgcn_readfirstlane(wv);

    const float4 qp = pts4[b * NN + q];
    const float4* __restrict__ cp = pts4 + (size_t)b * NN + (size_t)sl * 1024;

    float l0 = 3.0e38f, l1 = 3.0e38f, l2 = 3.0e38f, l3 = 3.0e38f;

    for (int i0 = 0; i0 < PRE; i0 += 8) {
#pragma unroll
        for (int u = 0; u < 8; ++u) {
            float4 c = cp[i0 + u];
            float dot = fmaf(qp.z, c.z, fmaf(qp.y, c.y, __fmul_rn(qp.x, c.x)));
            float d = __fadd_rn(__fsub_rn(qp.w, __fmul_rn(2.0f, dot)), c.w);
            if (d < l3) {
                bool b2 = d < l2, b1 = d < l1, b0 = d < l0;
                l3 = b2 ? l2 : d;
                l2 = b2 ? (b1 ? l1 : d) : l2;
                l1 = b1 ? (b0 ? l0 : d) : l1;
                l0 = b0 ? d : l0;
            }
        }
    }

    smem[(wv * 4 + 0) * 64 + lane] = l0;
    smem[(wv * 4 + 1) * 64 + lane] = l1;
    smem[(wv * 4 + 2) * 64 + lane] = l2;
    smem[(wv * 4 + 3) * 64 + lane] = l3;
    __syncthreads();

    if (t < QPB) {
        float h[8];
        int kc[8];
#pragma unroll
        for (int s = 0; s < 8; ++s) { h[s] = smem[(s * 4) * 64 + t]; kc[s] = 0; }
        float best = 3.0e38f;
        for (int o = 0; o < KK; ++o) {
            best = h[0]; int bs = 0;
#pragma unroll
            for (int s = 1; s < 8; ++s) { if (h[s] < best) { best = h[s]; bs = s; } }
#pragma unroll
            for (int s = 0; s < 8; ++s) {
                if (s == bs) {
                    kc[s]++;
                    h[s] = (kc[s] < 4) ? smem[(s * 4 + kc[s]) * 64 + t] : 3.0e38f;
                }
            }
        }
        thrb[(size_t)b * NN + blockIdx.x * QPB + t] = best;   // 16th of 32-subset
    }
}

// ---------------------------------------------------------------- knn K2: full scan vs float threshold
// grid (128,2,4) x 8 waves = 8192 waves (8/SIMD); wave = subslice s=z*8+wv,
// 256 candidates, 64 queries lane-parallel; candidate stream is wave-uniform
// scalar loads. Round-9 PMC: 4 waves/SIMD -> VALUBusy 38%, latency-bound.
__global__ __launch_bounds__(512) void knn_scan_kernel(
    const float4* __restrict__ pts4, const float* __restrict__ thrb,
    ushort* __restrict__ buf, ushort* __restrict__ cnt)
{
    const int t    = threadIdx.x;
    const int wv   = t >> 6;
    const int lane = t & 63;
    const int b    = blockIdx.y;
    const int q    = blockIdx.x * QPB + lane;          // within batch
    const int s    = __builtin_amdgcn_readfirstlane(blockIdx.z * 8 + wv);

    const float4 qp = pts4[b * NN + q];
    const float thr = thrb[(size_t)b * NN + q];
    const float4* __restrict__ cp = pts4 + (size_t)b * NN + (size_t)s * 256;
    const unsigned cbase = s * 256;

    const int cell = (((int)(b * NN) + q) << 5) + s;   // (global q)*32 + subslice
    ushort* __restrict__ bp = buf + (size_t)cell * CAP;
    int pend = 0;

    for (int i0 = 0; i0 < 256; i0 += 8) {
#pragma unroll
        for (int u = 0; u < 8; ++u) {
            const int ci = i0 + u;
            float4 c = cp[ci];
            float dot = fmaf(qp.z, c.z, fmaf(qp.y, c.y, __fmul_rn(qp.x, c.x)));
            float d = __fadd_rn(__fsub_rn(qp.w, __fmul_rn(2.0f, dot)), c.w);
            if (d <= thr) {
                if (pend < CAP) bp[pend] = (ushort)(cbase + ci);
                pend++;
            }
        }
    }
    cnt[cell] = (ushort)((pend < CAP) ? pend : CAP);
}

// ---------------------------------------------------------------- knn K3: exact select of survivors
// 512 blocks x 4 waves (2/SIMD); wave = 8 queries x 8 lane-groups (4 cells
// each); exact ull keys (idx tie-break), sorted-insert, 8-way merge.
__global__ __launch_bounds__(256) void knn_select_kernel(
    const float4* __restrict__ pts4, const ushort* __restrict__ buf,
    const ushort* __restrict__ cnt, int* __restrict__ iout)
{
    __shared__ ull sm3[4][8][8][KK];   // 32 KB

    const int t = threadIdx.x;
    const int wv = t >> 6, lane = t & 63;
    const int qq = lane & 7, hh = lane >> 3;
    const int q  = (blockIdx.x * 4 + wv) * 8 + qq;     // global query 0..16383
    const int b  = q >> 13;

    const float4 qp = pts4[q];
    ull list[KK];
#pragma unroll
    for (int i = 0; i < KK; ++i) list[i] = KINF;

#pragma unroll
    for (int ss = 0; ss < 4; ++ss) {
        const int s = hh * 4 + ss;
        const int cell = (q << 5) + s;
        const int n = cnt[cell];
        const ushort* bp = buf + (size_t)cell * CAP;
        for (int i = 0; i < n; ++i) {
            int id = bp[i];
            float4 c = pts4[b * NN + id];
            float dot = fmaf(qp.z, c.z, fmaf(qp.y, c.y, __fmul_rn(qp.x, c.x)));
            float d = __fadd_rn(__fsub_rn(qp.w, __fmul_rn(2.0f, dot)), c.w);
            unsigned ud = __float_as_uint(d);
            ud ^= ((unsigned)((int)ud >> 31)) | 0x80000000u;
            ull k = ((ull)ud << 32) | (unsigned)id;
#pragma unroll
            for (int i2 = KK - 1; i2 > 0; --i2) {
                bool c1 = k < list[i2];
                bool c2 = k < list[i2 - 1];
                ull nd = c2 ? list[i2 - 1] : k;
                list[i2] = c1 ? nd : list[i2];
            }
            list[0] = (k < list[0]) ? k : list[0];
        }
    }

#pragma unroll
    for (int k = 0; k < KK; ++k) sm3[wv][hh][qq][k] = list[k];

    if (hh == 0) {
        ull h[8]; int kc[8];
#pragma unroll
        for (int s = 0; s < 8; ++s) { h[s] = sm3[wv][s][qq][0]; kc[s] = 0; }
        int* op = iout + (size_t)q * KK;
        for (int o = 0; o < KK; ++o) {
            ull best = h[0]; int bs = 0;
#pragma unroll
            for (int s = 1; s < 8; ++s) { if (h[s] < best) { best = h[s]; bs = s; } }
            op[o] = (int)(unsigned)(best & 0xFFFFFFFFULL);
#pragma unroll
            for (int s = 0; s < 8; ++s) {
                if (s == bs) {
                    kc[s]++;
                    h[s] = (kc[s] < KK) ? sm3[wv][s][qq][kc[s]] : KINF;
                }
            }
        }
    }
}

// ---------------------------------------------------------------- f1 (bf16 output) — 256 blocks so every CU gets work
__global__ __launch_bounds__(64) void f1_kernel(
    const float* __restrict__ x,
    const float* __restrict__ w1, const float* __restrict__ b1,
    const float* __restrict__ w2, const float* __restrict__ b2,
    ushort* __restrict__ f1)
{
    int P = blockIdx.x * 64 + threadIdx.x;
    if (P >= BB * NN) return;
    int b = P >> 13, n = P & (NN - 1);
    float x0 = x[(b * 3 + 0) * NN + n];
    float x1 = x[(b * 3 + 1) * NN + n];
    float x2 = x[(b * 3 + 2) * NN + n];
    float h[32];
#pragma unroll
    for (int o = 0; o < 32; ++o) {
        float v = fmaf(w1[o * 3 + 2], x2, fmaf(w1[o * 3 + 1], x1, fmaf(w1[o * 3 + 0], x0, b1[o])));
        h[o] = fmaxf(v, 0.f);
    }
#pragma unroll
    for (int o4 = 0; o4 < 16; ++o4) {
        float vv[4];
#pragma unroll
        for (int u = 0; u < 4; ++u) {
            int o = o4 * 4 + u;
            float v = b2[o];
#pragma unroll
            for (int k = 0; k < 32; ++k) v = fmaf(w2[o * 32 + k], h[k], v);
            vv[u] = fmaxf(v, 0.f);
        }
        ushort4 s = { f2bf(vv[0]), f2bf(vv[1]), f2bf(vv[2]), f2bf(vv[3]) };
        *(ushort4*)(f1 + (size_t)P * 64 + o4 * 4) = s;
    }
}

// ---------------------------------------------------------------- attention A: gather + layer1 (w1 frags only -> no spill)
__global__ __launch_bounds__(256, 2) void attn_a_kernel(
    const ushort* __restrict__ f1, const int* __restrict__ idx,
    const float* __restrict__ aw1, const float* __restrict__ ab1,
    ushort* __restrict__ Hg, ushort* __restrict__ fkg)
{
    __shared__ __align__(16) ushort fkb[4][16][72];    // per-wave, stride 144 B

    const int t = threadIdx.x;
    const int wv = t >> 6, lane = t & 63;
    const int l15 = lane & 15, qd = lane >> 4;

    short8 w1f[8][2];
#pragma unroll
    for (int tile = 0; tile < 8; ++tile)
#pragma unroll
        for (int ks = 0; ks < 2; ++ks) {
            const float4* p = (const float4*)(aw1 + ((tile * 16 + l15) * 64 + ks * 32 + qd * 8));
            float4 A = p[0], B = p[1];
            short8 f;
            f[0] = f2bf(A.x); f[1] = f2bf(A.y); f[2] = f2bf(A.z); f[3] = f2bf(A.w);
            f[4] = f2bf(B.x); f[5] = f2bf(B.y); f[6] = f2bf(B.z); f[7] = f2bf(B.w);
            w1f[tile][ks] = f;
        }

    const int W = blockIdx.x * 4 + wv;
    for (int g = 0; g < 4; ++g) {
        const int P = W * 4 + g;
        const int b = P >> 13;

        float fc = bf2f(f1[(size_t)P * 64 + lane]);
        ushort fn[15];
#pragma unroll
        for (int j = 0; j < 15; ++j) {
            int nb = idx[(size_t)P * KK + 1 + j];
            fn[j] = f1[((size_t)b * NN + nb) * 64 + lane];
        }
        ushort* fkp = fkg + (size_t)P * 1024;
#pragma unroll
        for (int j = 0; j < 15; ++j) {
            ushort v = f2bf(bf2f(fn[j]) - fc);
            fkb[wv][j][lane] = v;
            fkp[j * 64 + lane] = v;                     // coalesced 128B row
        }
        fkb[wv][15][lane] = 0;
        fkp[15 * 64 + lane] = 0;

        short8 a0 = *(const short8*)&fkb[wv][l15][qd * 8];
        short8 a1 = *(const short8*)&fkb[wv][l15][32 + qd * 8];

        ushort* hp = Hg + (size_t)P * 2048;             // [j][128]
#pragma unroll
        for (int tile = 0; tile < 8; ++tile) {
            float bv = ab1[tile * 16 + l15];
            f32x4 acc = { bv, bv, bv, bv };
            acc = __builtin_amdgcn_mfma_f32_16x16x32_bf16(a0, w1f[tile][0], acc, 0, 0, 0);
            acc = __builtin_amdgcn_mfma_f32_16x16x32_bf16(a1, w1f[tile][1], acc, 0, 0, 0);
#pragma unroll
            for (int reg = 0; reg < 4; ++reg)
                hp[(qd * 4 + reg) * 128 + tile * 16 + l15] = f2bf(fmaxf(acc[reg], 0.f));
        }
    }
}

// ---------------------------------------------------------------- attention B: layer2 + softmax + aggregate (w2 frags only)
__global__ __launch_bounds__(256, 1) void attn_b_kernel(
    const ushort* __restrict__ Hg, const ushort* __restrict__ fkg,
    const float* __restrict__ aw2, const float* __restrict__ ab2,
    ushort* __restrict__ fagg)
{
    const int t = threadIdx.x;
    const int wv = t >> 6, lane = t & 63;
    const int l15 = lane & 15, qd = lane >> 4;

    short8 w2f[4][4];
#pragma unroll
    for (int tile = 0; tile < 4; ++tile)
#pragma unroll
        for (int ks = 0; ks < 4; ++ks) {
            const float4* p = (const float4*)(aw2 + ((tile * 16 + l15) * 128 + ks * 32 + qd * 8));
            float4 A = p[0], B = p[1];
            short8 f;
            f[0] = f2bf(A.x); f[1] = f2bf(A.y); f[2] = f2bf(A.z); f[3] = f2bf(A.w);
            f[4] = f2bf(B.x); f[5] = f2bf(B.y); f[6] = f2bf(B.z); f[7] = f2bf(B.w);
            w2f[tile][ks] = f;
        }

    const int W = blockIdx.x * 4 + wv;
    for (int g = 0; g < 4; ++g) {
        const int P = W * 4 + g;

        const ushort* hp = Hg + (size_t)P * 2048;
        short8 a2[4];
#pragma unroll
        for (int ks = 0; ks < 4; ++ks)
            a2[ks] = *(const short8*)(hp + l15 * 128 + ks * 32 + qd * 8);

        const ushort* fkp = fkg + (size_t)P * 1024;
        ushort fkv[4][4];
#pragma unroll
        for (int tile = 0; tile < 4; ++tile)
#pragma unroll
            for (int reg = 0; reg < 4; ++reg)
                fkv[tile][reg] = fkp[(qd * 4 + reg) * 64 + tile * 16 + l15];

        f32x4 L[4];
#pragma unroll
        for (int tile = 0; tile < 4; ++tile) {
            float bv = ab2[tile * 16 + l15];
            f32x4 acc = { bv, bv, bv, bv };
#pragma unroll
            for (int ks = 0; ks < 4; ++ks)
                acc = __builtin_amdgcn_mfma_f32_16x16x32_bf16(a2[ks], w2f[tile][ks], acc, 0, 0, 0);
            L[tile] = acc;
        }

        float fa[4];
#pragma unroll
        for (int tile = 0; tile < 4; ++tile) {
            float m1 = -3.0e38f;
#pragma unroll
            for (int reg = 0; reg < 4; ++reg)
                if (qd * 4 + reg < 15) m1 = fmaxf(m1, L[tile][reg]);
            m1 = fmaxf(m1, __shfl_xor(m1, 16));
            m1 = fmaxf(m1, __shfl_xor(m1, 32));
            float e[4], ssum = 0.f;
#pragma unroll
            for (int reg = 0; reg < 4; ++reg) {
                bool valid = (qd * 4 + reg < 15);
                e[reg] = valid ? __expf(L[tile][reg] - m1) : 0.f;
                ssum += e[reg];
            }
            ssum += __shfl_xor(ssum, 16);
            ssum += __shfl_xor(ssum, 32);
            float part = 0.f;
#pragma unroll
            for (int reg = 0; reg < 4; ++reg)
                part = fmaf(e[reg], bf2f(fkv[tile][reg]), part);
            part += __shfl_xor(part, 16);
            part += __shfl_xor(part, 32);
            fa[tile] = part / ssum;
        }
        if (qd == 0) {
#pragma unroll
            for (int tile = 0; tile < 4; ++tile)
                fagg[(size_t)P * 64 + tile * 16 + l15] = f2bf(fa[tile]);
        }
    }
}

// ---------------------------------------------------------------- cov + mlp2 (bf16 output) — 256 blocks
__global__ __launch_bounds__(64) void cov_kernel(
    const float4* __restrict__ pts4, const int* __restrict__ idx,
    const float* __restrict__ w, const float* __restrict__ bb,
    ushort* __restrict__ fcov)
{
    int P = blockIdx.x * 64 + threadIdx.x;
    if (P >= BB * NN) return;
    int b = P >> 13;
    const int4* ip4 = (const int4*)(idx + (size_t)P * KK);
    int ids[KK];
#pragma unroll
    for (int g = 0; g < 4; ++g) {
        int4 v = ip4[g];
        ids[g * 4 + 0] = v.x; ids[g * 4 + 1] = v.y;
        ids[g * 4 + 2] = v.z; ids[g * 4 + 3] = v.w;
    }
    float px[KK], py[KK], pz[KK];
#pragma unroll
    for (int k = 0; k < KK; ++k) {
        float4 c = pts4[b * NN + ids[k]];
        px[k] = c.x; py[k] = c.y; pz[k] = c.z;
    }
    float mx = 0.f, my = 0.f, mz = 0.f;
#pragma unroll
    for (int k = 0; k < KK; ++k) { mx += px[k]; my += py[k]; mz += pz[k]; }
    mx *= (1.f / 16.f); my *= (1.f / 16.f); mz *= (1.f / 16.f);
    float c00 = 0, c01 = 0, c02 = 0, c11 = 0, c12 = 0, c22 = 0;
#pragma unroll
    for (int k = 0; k < KK; ++k) {
        float dx = px[k] - mx, dy = py[k] - my, dz = pz[k] - mz;
        c00 = fmaf(dx, dx, c00); c01 = fmaf(dx, dy, c01); c02 = fmaf(dx, dz, c02);
        c11 = fmaf(dy, dy, c11); c12 = fmaf(dy, dz, c12); c22 = fmaf(dz, dz, c22);
    }
    const float inv = 1.f / 16.f;
    float cf[9] = { c00 * inv, c01 * inv, c02 * inv,
                    c01 * inv, c11 * inv, c12 * inv,
                    c02 * inv, c12 * inv, c22 * inv };
    ushort* out = fcov + (size_t)P * 32;
#pragma unroll
    for (int o = 0; o < 32; ++o) {
        float v = bb[o];
#pragma unroll
        for (int m = 0; m < 9; ++m) v = fmaf(w[o * 9 + m], cf[m], v);
        out[o] = f2bf(fmaxf(v, 0.f));
    }
}

// ---------------------------------------------------------------- mlp3 + output (bf16 MFMA) — verified round 6
__global__ __launch_bounds__(256) void mlp3_kernel(
    const ushort* __restrict__ fagg, const ushort* __restrict__ fcov,
    const float* __restrict__ w1, const float* __restrict__ b1,
    const float* __restrict__ w2, const float* __restrict__ b2,
    const float* __restrict__ x, float* __restrict__ out)
{
    __shared__ __align__(16) ushort fb[4][16][104];    // 13.3 KB
    __shared__ __align__(16) ushort hb[4][16][136];    // 17.4 KB

    const int t = threadIdx.x;
    const int wv = t >> 6, lane = t & 63;
    const int l15 = lane & 15, qd = lane >> 4;

    short8 w1f[8][3];
#pragma unroll
    for (int tile = 0; tile < 8; ++tile)
#pragma unroll
        for (int ks = 0; ks < 3; ++ks) {
            const float* p = w1 + ((size_t)(tile * 16 + l15) * 96 + ks * 32 + qd * 8);
            float4 A = *(const float4*)p, B = *(const float4*)(p + 4);
            short8 f;
            f[0] = f2bf(A.x); f[1] = f2bf(A.y); f[2] = f2bf(A.z); f[3] = f2bf(A.w);
            f[4] = f2bf(B.x); f[5] = f2bf(B.y); f[6] = f2bf(B.z); f[7] = f2bf(B.w);
            w1f[tile][ks] = f;
        }
    short8 w2f[4];
#pragma unroll
    for (int ks = 0; ks < 4; ++ks) {
        short8 f = {};
        if (l15 < 12) {
            const float* p = w2 + ((size_t)l15 * 128 + ks * 32 + qd * 8);
            float4 A = *(const float4*)p, B = *(const float4*)(p + 4);
            f[0] = f2bf(A.x); f[1] = f2bf(A.y); f[2] = f2bf(A.z); f[3] = f2bf(A.w);
            f[4] = f2bf(B.x); f[5] = f2bf(B.y); f[6] = f2bf(B.z); f[7] = f2bf(B.w);
        }
        w2f[ks] = f;
    }

    const int T = blockIdx.x * 4 + wv;    // tile 0..1023

    // ---- stage f = [fagg | fcov] (already bf16) into A-layout
    {
        const int pt = lane >> 2, c4 = lane & 3;
        const ushort* fap = fagg + ((size_t)(T * 16 + pt) * 64 + c4 * 16);
        *(short8*)&fb[wv][pt][c4 * 16]     = *(const short8*)(fap);
        *(short8*)&fb[wv][pt][c4 * 16 + 8] = *(const short8*)(fap + 8);
        const ushort* fcp = fcov + ((size_t)(T * 16 + pt) * 32 + c4 * 8);
        *(short8*)&fb[wv][pt][64 + c4 * 8] = *(const short8*)(fcp);
    }

    short8 a[3];
#pragma unroll
    for (int ks = 0; ks < 3; ++ks)
        a[ks] = *(const short8*)&fb[wv][l15][ks * 32 + qd * 8];

#pragma unroll
    for (int tile = 0; tile < 8; ++tile) {
        float bv = b1[tile * 16 + l15];
        f32x4 acc = { bv, bv, bv, bv };
#pragma unroll
        for (int ks = 0; ks < 3; ++ks)
            acc = __builtin_amdgcn_mfma_f32_16x16x32_bf16(a[ks], w1f[tile][ks], acc, 0, 0, 0);
#pragma unroll
        for (int reg = 0; reg < 4; ++reg)
            hb[wv][qd * 4 + reg][tile * 16 + l15] = f2bf(fmaxf(acc[reg], 0.f));
    }

    short8 a2[4];
#pragma unroll
    for (int ks = 0; ks < 4; ++ks)
        a2[ks] = *(const short8*)&hb[wv][l15][ks * 32 + qd * 8];

    float bv2 = (l15 < 12) ? b2[l15] : 0.f;
    f32x4 acc = { bv2, bv2, bv2, bv2 };
#pragma unroll
    for (int ks = 0; ks < 4; ++ks)
        acc = __builtin_amdgcn_mfma_f32_16x16x32_bf16(a2[ks], w2f[ks], acc, 0, 0, 0);

    if (l15 < 12) {
        const int c = l15 >> 2, rr = l15 & 3;
#pragma unroll
        for (int reg = 0; reg < 4; ++reg) {
            int P = T * 16 + qd * 4 + reg;
            int b = P >> 13, n = P & (NN - 1);
            float xv = x[((size_t)b * 3 + c) * NN + n];
            out[(((size_t)b * 3 + c) * 4 + rr) * NN + n] = xv + 0.15f * acc[reg];
        }
    }
}

// ---------------------------------------------------------------- launch
extern "C" void kernel_launch(void* const* d_in, const int* in_sizes, int n_in,
                              void* d_out, int out_size, void* d_ws, size_t ws_size,
                              hipStream_t stream)
{
    (void)in_sizes; (void)n_in; (void)out_size; (void)ws_size;
    const float* x    = (const float*)d_in[0];
    const float* m1w1 = (const float*)d_in[1];
    const float* m1b1 = (const float*)d_in[2];
    const float* m1w2 = (const float*)d_in[3];
    const float* m1b2 = (const float*)d_in[4];
    const float* m2w1 = (const float*)d_in[5];
    const float* m2b1 = (const float*)d_in[6];
    const float* m3w1 = (const float*)d_in[7];
    const float* m3b1 = (const float*)d_in[8];
    const float* m3w2 = (const float*)d_in[9];
    const float* m3b2 = (const float*)d_in[10];
    const float* aw1  = (const float*)d_in[11];
    const float* ab1  = (const float*)d_in[12];
    const float* aw2  = (const float*)d_in[13];
    const float* ab2  = (const float*)d_in[14];
    float* out = (float*)d_out;

    // bufb (survivors) is dead after knn_select; fkg+Hg alias into it.
    char* ws = (char*)d_ws;
    float4* pts4 = (float4*)(ws + 0);             //   262144 B
    float*  thrb = (float*)(ws + 262144);         //    65536 B
    int*    idxb = (int*)  (ws + 327680);         //  1048576 B
    ushort* cntb = (ushort*)(ws + 1376256);       //  1048576 B (512K cells)
    ushort* bufb = (ushort*)(ws + 2424832);       // 10485760 B (CAP 10)
    ushort* fkg  = (ushort*)(ws + 2424832);       //  [alias]  2097152 B
    ushort* Hg   = (ushort*)(ws + 4521984);       //  [alias]  4194304 B
    ushort* f1b  = (ushort*)(ws + 12910592);      //  2097152 B
    ushort* fagg = (ushort*)(ws + 15007744);      //  2097152 B
    ushort* fcov = (ushort*)(ws + 17104896);      //  1048576 B  (end 18.2 MB)

    prep_kernel<<<64, 256, 0, stream>>>(x, pts4);
    knn_prefix_kernel<<<dim3(NN / QPB, BB), 512, 0, stream>>>(pts4, thrb);
    knn_scan_kernel<<<dim3(NN / QPB, BB, 4), 512, 0, stream>>>(pts4, thrb, bufb, cntb);
    knn_select_kernel<<<512, 256, 0, stream>>>(pts4, bufb, cntb, idxb);
    f1_kernel<<<256, 64, 0, stream>>>(x, m1w1, m1b1, m1w2, m1b2, f1b);
    attn_a_kernel<<<1024, 256, 0, stream>>>(f1b, idxb, aw1, ab1, Hg, fkg);
    attn_b_kernel<<<1024, 256, 0, stream>>>(Hg, fkg, aw2, ab2, fagg);
    cov_kernel<<<256, 64, 0, stream>>>(pts4, idxb, m2w1, m2b1, fcov);
    mlp3_kernel<<<256, 256, 0, stream>>>(fagg, fcov, m3w1, m3b1, m3w2, m3b2, x, out);
}

// Round 11
// 272.609 us; speedup vs baseline: 1.5485x; 1.1359x over previous
//
#include <hip/hip_runtime.h>

#define BB 2
#define NN 8192
#define KK 16
#define QPB 64
#define PRE 256          // prefix candidates sampled per 1024-slice (8 -> 2048 sample)
#define NSL 32           // K2/K3 subslices per query (256 candidates each)
#define CAP 10           // buffered survivors per (query, subslice); lambda~2.2
typedef unsigned long long ull;
typedef unsigned short ushort;
#define KINF 0xFFFFFFFFFFFFFFFFULL

typedef __attribute__((ext_vector_type(8))) short short8;
typedef __attribute__((ext_vector_type(4))) float f32x4;

static __device__ __forceinline__ ushort f2bf(float f) {
    unsigned u = __float_as_uint(f);
    unsigned r = (u + 0x7FFFu + ((u >> 16) & 1u)) >> 16;
    return (ushort)r;
}
static __device__ __forceinline__ float bf2f(ushort s) {
    return __uint_as_float(((unsigned)s) << 16);
}

// ---------------------------------------------------------------- prep
__global__ __launch_bounds__(256) void prep_kernel(
    const float* __restrict__ x, float4* __restrict__ pts4)
{
    int t = blockIdx.x * 256 + threadIdx.x;
    if (t < BB * NN) {
        int b = t >> 13, n = t & (NN - 1);
        float x0 = x[(b * 3 + 0) * NN + n];
        float x1 = x[(b * 3 + 1) * NN + n];
        float x2 = x[(b * 3 + 2) * NN + n];
        // same fmaf chain as the knn dot so that d(self) == 0 bit-exactly
        float sq = fmaf(x2, x2, fmaf(x1, x1, __fmul_rn(x0, x0)));
        pts4[t] = make_float4(x0, x1, x2, sq);
    }
}

// ---------------------------------------------------------------- knn K1: prefix -> conservative per-query threshold (float)
__global__ __launch_bounds__(512) void knn_prefix_kernel(
    const float4* __restrict__ pts4, float* __restrict__ thrb)
{
    __shared__ float smem[8 * 4 * 64];   // [wave][rank][query], 8 KB

    const int t    = threadIdx.x;
    const int wv   = t >> 6;
    const int lane = t & 63;
    const int b    = blockIdx.y;
    const int q    = blockIdx.x * QPB + lane;
    const int sl   = __builtin_amdgcn_readfirstlane(wv);

    const float4 qp = pts4[b * NN + q];
    const float4* __restrict__ cp = pts4 + (size_t)b * NN + (size_t)sl * 1024;

    float l0 = 3.0e38f, l1 = 3.0e38f, l2 = 3.0e38f, l3 = 3.0e38f;

    for (int i0 = 0; i0 < PRE; i0 += 8) {
#pragma unroll
        for (int u = 0; u < 8; ++u) {
            float4 c = cp[i0 + u];
            float dot = fmaf(qp.z, c.z, fmaf(qp.y, c.y, __fmul_rn(qp.x, c.x)));
            float d = __fadd_rn(__fsub_rn(qp.w, __fmul_rn(2.0f, dot)), c.w);
            if (d < l3) {
                bool b2 = d < l2, b1 = d < l1, b0 = d < l0;
                l3 = b2 ? l2 : d;
                l2 = b2 ? (b1 ? l1 : d) : l2;
                l1 = b1 ? (b0 ? l0 : d) : l1;
                l0 = b0 ? d : l0;
            }
        }
    }

    smem[(wv * 4 + 0) * 64 + lane] = l0;
    smem[(wv * 4 + 1) * 64 + lane] = l1;
    smem[(wv * 4 + 2) * 64 + lane] = l2;
    smem[(wv * 4 + 3) * 64 + lane] = l3;
    __syncthreads();

    if (t < QPB) {
        float h[8];
        int kc[8];
#pragma unroll
        for (int s = 0; s < 8; ++s) { h[s] = smem[(s * 4) * 64 + t]; kc[s] = 0; }
        float best = 3.0e38f;
        for (int o = 0; o < KK; ++o) {
            best = h[0]; int bs = 0;
#pragma unroll
            for (int s = 1; s < 8; ++s) { if (h[s] < best) { best = h[s]; bs = s; } }
#pragma unroll
            for (int s = 0; s < 8; ++s) {
                if (s == bs) {
                    kc[s]++;
                    h[s] = (kc[s] < 4) ? smem[(s * 4 + kc[s]) * 64 + t] : 3.0e38f;
                }
            }
        }
        thrb[(size_t)b * NN + blockIdx.x * QPB + t] = best;   // 16th of 32-subset
    }
}

// ---------------------------------------------------------------- knn K2: full scan vs float threshold
__global__ __launch_bounds__(512) void knn_scan_kernel(
    const float4* __restrict__ pts4, const float* __restrict__ thrb,
    ushort* __restrict__ buf, ushort* __restrict__ cnt)
{
    const int t    = threadIdx.x;
    const int wv   = t >> 6;
    const int lane = t & 63;
    const int b    = blockIdx.y;
    const int q    = blockIdx.x * QPB + lane;          // within batch
    const int s    = __builtin_amdgcn_readfirstlane(blockIdx.z * 8 + wv);

    const float4 qp = pts4[b * NN + q];
    const float thr = thrb[(size_t)b * NN + q];
    const float4* __restrict__ cp = pts4 + (size_t)b * NN + (size_t)s * 256;
    const unsigned cbase = s * 256;

    const int cell = (((int)(b * NN) + q) << 5) + s;   // (global q)*32 + subslice
    ushort* __restrict__ bp = buf + (size_t)cell * CAP;
    int pend = 0;

    for (int i0 = 0; i0 < 256; i0 += 8) {
#pragma unroll
        for (int u = 0; u < 8; ++u) {
            const int ci = i0 + u;
            float4 c = cp[ci];
            float dot = fmaf(qp.z, c.z, fmaf(qp.y, c.y, __fmul_rn(qp.x, c.x)));
            float d = __fadd_rn(__fsub_rn(qp.w, __fmul_rn(2.0f, dot)), c.w);
            if (d <= thr) {
                if (pend < CAP) bp[pend] = (ushort)(cbase + ci);
                pend++;
            }
        }
    }
    cnt[cell] = (ushort)((pend < CAP) ? pend : CAP);
}

// ---------------------------------------------------------------- knn K3: exact select of survivors
__global__ __launch_bounds__(256) void knn_select_kernel(
    const float4* __restrict__ pts4, const ushort* __restrict__ buf,
    const ushort* __restrict__ cnt, int* __restrict__ iout)
{
    __shared__ ull sm3[4][8][8][KK];   // 32 KB

    const int t = threadIdx.x;
    const int wv = t >> 6, lane = t & 63;
    const int qq = lane & 7, hh = lane >> 3;
    const int q  = (blockIdx.x * 4 + wv) * 8 + qq;     // global query 0..16383
    const int b  = q >> 13;

    const float4 qp = pts4[q];
    ull list[KK];
#pragma unroll
    for (int i = 0; i < KK; ++i) list[i] = KINF;

#pragma unroll
    for (int ss = 0; ss < 4; ++ss) {
        const int s = hh * 4 + ss;
        const int cell = (q << 5) + s;
        const int n = cnt[cell];
        const ushort* bp = buf + (size_t)cell * CAP;
        for (int i = 0; i < n; ++i) {
            int id = bp[i];
            float4 c = pts4[b * NN + id];
            float dot = fmaf(qp.z, c.z, fmaf(qp.y, c.y, __fmul_rn(qp.x, c.x)));
            float d = __fadd_rn(__fsub_rn(qp.w, __fmul_rn(2.0f, dot)), c.w);
            unsigned ud = __float_as_uint(d);
            ud ^= ((unsigned)((int)ud >> 31)) | 0x80000000u;
            ull k = ((ull)ud << 32) | (unsigned)id;
#pragma unroll
            for (int i2 = KK - 1; i2 > 0; --i2) {
                bool c1 = k < list[i2];
                bool c2 = k < list[i2 - 1];
                ull nd = c2 ? list[i2 - 1] : k;
                list[i2] = c1 ? nd : list[i2];
            }
            list[0] = (k < list[0]) ? k : list[0];
        }
    }

#pragma unroll
    for (int k = 0; k < KK; ++k) sm3[wv][hh][qq][k] = list[k];

    if (hh == 0) {
        ull h[8]; int kc[8];
#pragma unroll
        for (int s = 0; s < 8; ++s) { h[s] = sm3[wv][s][qq][0]; kc[s] = 0; }
        int* op = iout + (size_t)q * KK;
        for (int o = 0; o < KK; ++o) {
            ull best = h[0]; int bs = 0;
#pragma unroll
            for (int s = 1; s < 8; ++s) { if (h[s] < best) { best = h[s]; bs = s; } }
            op[o] = (int)(unsigned)(best & 0xFFFFFFFFULL);
#pragma unroll
            for (int s = 0; s < 8; ++s) {
                if (s == bs) {
                    kc[s]++;
                    h[s] = (kc[s] < KK) ? sm3[wv][s][qq][kc[s]] : KINF;
                }
            }
        }
    }
}

// ---------------------------------------------------------------- f1 (bf16 output)
__global__ __launch_bounds__(64) void f1_kernel(
    const float* __restrict__ x,
    const float* __restrict__ w1, const float* __restrict__ b1,
    const float* __restrict__ w2, const float* __restrict__ b2,
    ushort* __restrict__ f1)
{
    int P = blockIdx.x * 64 + threadIdx.x;
    if (P >= BB * NN) return;
    int b = P >> 13, n = P & (NN - 1);
    float x0 = x[(b * 3 + 0) * NN + n];
    float x1 = x[(b * 3 + 1) * NN + n];
    float x2 = x[(b * 3 + 2) * NN + n];
    float h[32];
#pragma unroll
    for (int o = 0; o < 32; ++o) {
        float v = fmaf(w1[o * 3 + 2], x2, fmaf(w1[o * 3 + 1], x1, fmaf(w1[o * 3 + 0], x0, b1[o])));
        h[o] = fmaxf(v, 0.f);
    }
#pragma unroll
    for (int o4 = 0; o4 < 16; ++o4) {
        float vv[4];
#pragma unroll
        for (int u = 0; u < 4; ++u) {
            int o = o4 * 4 + u;
            float v = b2[o];
#pragma unroll
            for (int k = 0; k < 32; ++k) v = fmaf(w2[o * 32 + k], h[k], v);
            vv[u] = fmaxf(v, 0.f);
        }
        ushort4 s = { f2bf(vv[0]), f2bf(vv[1]), f2bf(vv[2]), f2bf(vv[3]) };
        *(ushort4*)(f1 + (size_t)P * 64 + o4 * 4) = s;
    }
}

// ---------------------------------------------------------------- attention (fused, weights in LDS)
// Round-8 lesson: both weight-frag sets in VGPRs (128) -> compiler's 128-reg
// target spills. Fix: weights live in padded LDS (stride = 4 mod 32 words,
// 2-way-free banks); B-frags come via ds_read_b128. Live VGPRs ~80 -> no
// spill. LDS 61 KB -> 2 blocks/CU, 8 waves/CU. Math identical to the
// verified round-4/6 attention (same layouts, same bf16 roundings).
__global__ __launch_bounds__(256, 2) void attn_kernel(
    const ushort* __restrict__ f1, const int* __restrict__ idx,
    const float* __restrict__ aw1, const float* __restrict__ ab1,
    const float* __restrict__ aw2, const float* __restrict__ ab2,
    ushort* __restrict__ fagg)
{
    __shared__ __align__(16) ushort w1l[128][72];      // 18.0 KB, layer1 weights
    __shared__ __align__(16) ushort w2l[64][136];      // 17.0 KB, layer2 weights
    __shared__ __align__(16) ushort fkb[4][16][72];    //  9.0 KB
    __shared__ __align__(16) ushort hb[4][16][136];    // 17.0 KB

    const int t = threadIdx.x;
    const int wv = t >> 6, lane = t & 63;
    const int l15 = lane & 15, qd = lane >> 4;

    // ---- stage weights to LDS (once per block)
    for (int i = t; i < 128 * 64; i += 256) {
        int r = i >> 6, c = i & 63;
        w1l[r][c] = f2bf(aw1[i]);
    }
    for (int i = t; i < 64 * 128; i += 256) {
        int r = i >> 7, c = i & 127;
        w2l[r][c] = f2bf(aw2[i]);
    }
    __syncthreads();

    const int W = blockIdx.x * 4 + wv;
    for (int g = 0; g < 8; ++g) {
        const int P = W * 8 + g;
        const int b = P >> 13;

        // ---- gather fk (wave-uniform neighbor rows -> coalesced 128B)
        float fc = bf2f(f1[(size_t)P * 64 + lane]);
        ushort fn[15];
#pragma unroll
        for (int j = 0; j < 15; ++j) {
            int nb = idx[(size_t)P * KK + 1 + j];
            fn[j] = f1[((size_t)b * NN + nb) * 64 + lane];
        }
#pragma unroll
        for (int j = 0; j < 15; ++j) fkb[wv][j][lane] = f2bf(bf2f(fn[j]) - fc);
        fkb[wv][15][lane] = 0;

        short8 a0 = *(const short8*)&fkb[wv][l15][qd * 8];
        short8 a1 = *(const short8*)&fkb[wv][l15][32 + qd * 8];

        // ---- layer 1 MFMA (B-frags from LDS) -> relu -> hb
#pragma unroll
        for (int tile = 0; tile < 8; ++tile) {
            float bv = ab1[tile * 16 + l15];
            f32x4 acc = { bv, bv, bv, bv };
            short8 b0 = *(const short8*)&w1l[tile * 16 + l15][qd * 8];
            short8 b1f = *(const short8*)&w1l[tile * 16 + l15][32 + qd * 8];
            acc = __builtin_amdgcn_mfma_f32_16x16x32_bf16(a0, b0, acc, 0, 0, 0);
            acc = __builtin_amdgcn_mfma_f32_16x16x32_bf16(a1, b1f, acc, 0, 0, 0);
#pragma unroll
            for (int reg = 0; reg < 4; ++reg)
                hb[wv][qd * 4 + reg][tile * 16 + l15] = f2bf(fmaxf(acc[reg], 0.f));
        }

        // ---- layer 2 MFMA
        short8 a2[4];
#pragma unroll
        for (int ks = 0; ks < 4; ++ks)
            a2[ks] = *(const short8*)&hb[wv][l15][ks * 32 + qd * 8];

        f32x4 L[4];
#pragma unroll
        for (int tile = 0; tile < 4; ++tile) {
            float bv = ab2[tile * 16 + l15];
            f32x4 acc = { bv, bv, bv, bv };
#pragma unroll
            for (int ks = 0; ks < 4; ++ks) {
                short8 bf = *(const short8*)&w2l[tile * 16 + l15][ks * 32 + qd * 8];
                acc = __builtin_amdgcn_mfma_f32_16x16x32_bf16(a2[ks], bf, acc, 0, 0, 0);
            }
            L[tile] = acc;
        }

        // ---- softmax over j=0..14 (row m = qd*4+reg, col c = tile*16+l15)
        float fa[4];
#pragma unroll
        for (int tile = 0; tile < 4; ++tile) {
            float m1 = -3.0e38f;
#pragma unroll
            for (int reg = 0; reg < 4; ++reg)
                if (qd * 4 + reg < 15) m1 = fmaxf(m1, L[tile][reg]);
            m1 = fmaxf(m1, __shfl_xor(m1, 16));
            m1 = fmaxf(m1, __shfl_xor(m1, 32));
            float e[4], ssum = 0.f;
#pragma unroll
            for (int reg = 0; reg < 4; ++reg) {
                bool valid = (qd * 4 + reg < 15);
                e[reg] = valid ? __expf(L[tile][reg] - m1) : 0.f;
                ssum += e[reg];
            }
            ssum += __shfl_xor(ssum, 16);
            ssum += __shfl_xor(ssum, 32);
            float part = 0.f;
#pragma unroll
            for (int reg = 0; reg < 4; ++reg) {
                float fkv = bf2f(fkb[wv][qd * 4 + reg][tile * 16 + l15]);
                part = fmaf(e[reg], fkv, part);
            }
            part += __shfl_xor(part, 16);
            part += __shfl_xor(part, 32);
            fa[tile] = part / ssum;
        }
        if (qd == 0) {
#pragma unroll
            for (int tile = 0; tile < 4; ++tile)
                fagg[(size_t)P * 64 + tile * 16 + l15] = f2bf(fa[tile]);
        }
    }
}

// ---------------------------------------------------------------- cov + mlp2 (bf16 output)
__global__ __launch_bounds__(64) void cov_kernel(
    const float4* __restrict__ pts4, const int* __restrict__ idx,
    const float* __restrict__ w, const float* __restrict__ bb,
    ushort* __restrict__ fcov)
{
    int P = blockIdx.x * 64 + threadIdx.x;
    if (P >= BB * NN) return;
    int b = P >> 13;
    const int4* ip4 = (const int4*)(idx + (size_t)P * KK);
    int ids[KK];
#pragma unroll
    for (int g = 0; g < 4; ++g) {
        int4 v = ip4[g];
        ids[g * 4 + 0] = v.x; ids[g * 4 + 1] = v.y;
        ids[g * 4 + 2] = v.z; ids[g * 4 + 3] = v.w;
    }
    float px[KK], py[KK], pz[KK];
#pragma unroll
    for (int k = 0; k < KK; ++k) {
        float4 c = pts4[b * NN + ids[k]];
        px[k] = c.x; py[k] = c.y; pz[k] = c.z;
    }
    float mx = 0.f, my = 0.f, mz = 0.f;
#pragma unroll
    for (int k = 0; k < KK; ++k) { mx += px[k]; my += py[k]; mz += pz[k]; }
    mx *= (1.f / 16.f); my *= (1.f / 16.f); mz *= (1.f / 16.f);
    float c00 = 0, c01 = 0, c02 = 0, c11 = 0, c12 = 0, c22 = 0;
#pragma unroll
    for (int k = 0; k < KK; ++k) {
        float dx = px[k] - mx, dy = py[k] - my, dz = pz[k] - mz;
        c00 = fmaf(dx, dx, c00); c01 = fmaf(dx, dy, c01); c02 = fmaf(dx, dz, c02);
        c11 = fmaf(dy, dy, c11); c12 = fmaf(dy, dz, c12); c22 = fmaf(dz, dz, c22);
    }
    const float inv = 1.f / 16.f;
    float cf[9] = { c00 * inv, c01 * inv, c02 * inv,
                    c01 * inv, c11 * inv, c12 * inv,
                    c02 * inv, c12 * inv, c22 * inv };
    ushort* out = fcov + (size_t)P * 32;
#pragma unroll
    for (int o = 0; o < 32; ++o) {
        float v = bb[o];
#pragma unroll
        for (int m = 0; m < 9; ++m) v = fmaf(w[o * 9 + m], cf[m], v);
        out[o] = f2bf(fmaxf(v, 0.f));
    }
}

// ---------------------------------------------------------------- mlp3 + output (bf16 MFMA) — verified round 6
__global__ __launch_bounds__(256) void mlp3_kernel(
    const ushort* __restrict__ fagg, const ushort* __restrict__ fcov,
    const float* __restrict__ w1, const float* __restrict__ b1,
    const float* __restrict__ w2, const float* __restrict__ b2,
    const float* __restrict__ x, float* __restrict__ out)
{
    __shared__ __align__(16) ushort fb[4][16][104];    // 13.3 KB
    __shared__ __align__(16) ushort hb[4][16][136];    // 17.4 KB

    const int t = threadIdx.x;
    const int wv = t >> 6, lane = t & 63;
    const int l15 = lane & 15, qd = lane >> 4;

    short8 w1f[8][3];
#pragma unroll
    for (int tile = 0; tile < 8; ++tile)
#pragma unroll
        for (int ks = 0; ks < 3; ++ks) {
            const float* p = w1 + ((size_t)(tile * 16 + l15) * 96 + ks * 32 + qd * 8);
            float4 A = *(const float4*)p, B = *(const float4*)(p + 4);
            short8 f;
            f[0] = f2bf(A.x); f[1] = f2bf(A.y); f[2] = f2bf(A.z); f[3] = f2bf(A.w);
            f[4] = f2bf(B.x); f[5] = f2bf(B.y); f[6] = f2bf(B.z); f[7] = f2bf(B.w);
            w1f[tile][ks] = f;
        }
    short8 w2f[4];
#pragma unroll
    for (int ks = 0; ks < 4; ++ks) {
        short8 f = {};
        if (l15 < 12) {
            const float* p = w2 + ((size_t)l15 * 128 + ks * 32 + qd * 8);
            float4 A = *(const float4*)p, B = *(const float4*)(p + 4);
            f[0] = f2bf(A.x); f[1] = f2bf(A.y); f[2] = f2bf(A.z); f[3] = f2bf(A.w);
            f[4] = f2bf(B.x); f[5] = f2bf(B.y); f[6] = f2bf(B.z); f[7] = f2bf(B.w);
        }
        w2f[ks] = f;
    }

    const int T = blockIdx.x * 4 + wv;    // tile 0..1023

    // ---- stage f = [fagg | fcov] (already bf16) into A-layout
    {
        const int pt = lane >> 2, c4 = lane & 3;
        const ushort* fap = fagg + ((size_t)(T * 16 + pt) * 64 + c4 * 16);
        *(short8*)&fb[wv][pt][c4 * 16]     = *(const short8*)(fap);
        *(short8*)&fb[wv][pt][c4 * 16 + 8] = *(const short8*)(fap + 8);
        const ushort* fcp = fcov + ((size_t)(T * 16 + pt) * 32 + c4 * 8);
        *(short8*)&fb[wv][pt][64 + c4 * 8] = *(const short8*)(fcp);
    }

    short8 a[3];
#pragma unroll
    for (int ks = 0; ks < 3; ++ks)
        a[ks] = *(const short8*)&fb[wv][l15][ks * 32 + qd * 8];

#pragma unroll
    for (int tile = 0; tile < 8; ++tile) {
        float bv = b1[tile * 16 + l15];
        f32x4 acc = { bv, bv, bv, bv };
#pragma unroll
        for (int ks = 0; ks < 3; ++ks)
            acc = __builtin_amdgcn_mfma_f32_16x16x32_bf16(a[ks], w1f[tile][ks], acc, 0, 0, 0);
#pragma unroll
        for (int reg = 0; reg < 4; ++reg)
            hb[wv][qd * 4 + reg][tile * 16 + l15] = f2bf(fmaxf(acc[reg], 0.f));
    }

    short8 a2[4];
#pragma unroll
    for (int ks = 0; ks < 4; ++ks)
        a2[ks] = *(const short8*)&hb[wv][l15][ks * 32 + qd * 8];

    float bv2 = (l15 < 12) ? b2[l15] : 0.f;
    f32x4 acc = { bv2, bv2, bv2, bv2 };
#pragma unroll
    for (int ks = 0; ks < 4; ++ks)
        acc = __builtin_amdgcn_mfma_f32_16x16x32_bf16(a2[ks], w2f[ks], acc, 0, 0, 0);

    if (l15 < 12) {
        const int c = l15 >> 2, rr = l15 & 3;
#pragma unroll
        for (int reg = 0; reg < 4; ++reg) {
            int P = T * 16 + qd * 4 + reg;
            int b = P >> 13, n = P & (NN - 1);
            float xv = x[((size_t)b * 3 + c) * NN + n];
            out[(((size_t)b * 3 + c) * 4 + rr) * NN + n] = xv + 0.15f * acc[reg];
        }
    }
}

// ---------------------------------------------------------------- launch
extern "C" void kernel_launch(void* const* d_in, const int* in_sizes, int n_in,
                              void* d_out, int out_size, void* d_ws, size_t ws_size,
                              hipStream_t stream)
{
    (void)in_sizes; (void)n_in; (void)out_size; (void)ws_size;
    const float* x    = (const float*)d_in[0];
    const float* m1w1 = (const float*)d_in[1];
    const float* m1b1 = (const float*)d_in[2];
    const float* m1w2 = (const float*)d_in[3];
    const float* m1b2 = (const float*)d_in[4];
    const float* m2w1 = (const float*)d_in[5];
    const float* m2b1 = (const float*)d_in[6];
    const float* m3w1 = (const float*)d_in[7];
    const float* m3b1 = (const float*)d_in[8];
    const float* m3w2 = (const float*)d_in[9];
    const float* m3b2 = (const float*)d_in[10];
    const float* aw1  = (const float*)d_in[11];
    const float* ab1  = (const float*)d_in[12];
    const float* aw2  = (const float*)d_in[13];
    const float* ab2  = (const float*)d_in[14];
    float* out = (float*)d_out;

    char* ws = (char*)d_ws;
    float4* pts4 = (float4*)(ws + 0);             //   262144 B
    float*  thrb = (float*)(ws + 262144);         //    65536 B
    int*    idxb = (int*)  (ws + 327680);         //  1048576 B
    ushort* cntb = (ushort*)(ws + 1376256);       //  1048576 B (512K cells)
    ushort* bufb = (ushort*)(ws + 2424832);       // 10485760 B (CAP 10)
    ushort* f1b  = (ushort*)(ws + 12910592);      //  2097152 B
    ushort* fagg = (ushort*)(ws + 15007744);      //  2097152 B
    ushort* fcov = (ushort*)(ws + 17104896);      //  1048576 B  (end 18.2 MB)

    prep_kernel<<<64, 256, 0, stream>>>(x, pts4);
    knn_prefix_kernel<<<dim3(NN / QPB, BB), 512, 0, stream>>>(pts4, thrb);
    knn_scan_kernel<<<dim3(NN / QPB, BB, 4), 512, 0, stream>>>(pts4, thrb, bufb, cntb);
    knn_select_kernel<<<512, 256, 0, stream>>>(pts4, bufb, cntb, idxb);
    f1_kernel<<<256, 64, 0, stream>>>(x, m1w1, m1b1, m1w2, m1b2, f1b);
    attn_kernel<<<512, 256, 0, stream>>>(f1b, idxb, aw1, ab1, aw2, ab2, fagg);
    cov_kernel<<<256, 64, 0, stream>>>(pts4, idxb, m2w1, m2b1, fcov);
    mlp3_kernel<<<256, 256, 0, stream>>>(fagg, fcov, m3w1, m3b1, m3w2, m3b2, x, out);
}

// Round 12
// 268.980 us; speedup vs baseline: 1.5694x; 1.0135x over previous
//
#include <hip/hip_runtime.h>

#define BB 2
#define NN 8192
#define KK 16
#define QPB 64
#define PRE 256          // prefix candidates sampled per 1024-slice
#define CAP 10           // buffered survivors per (query, subslice); lambda~2.2
typedef unsigned long long ull;
typedef unsigned short ushort;
#define KINF 0xFFFFFFFFFFFFFFFFULL

typedef __attribute__((ext_vector_type(8))) short short8;
typedef __attribute__((ext_vector_type(4))) float f32x4;

static __device__ __forceinline__ ushort f2bf(float f) {
    unsigned u = __float_as_uint(f);
    unsigned r = (u + 0x7FFFu + ((u >> 16) & 1u)) >> 16;
    return (ushort)r;
}
static __device__ __forceinline__ float bf2f(ushort s) {
    return __uint_as_float(((unsigned)s) << 16);
}

// distance form used by prefix/scan/select (consistent => thr conservative):
// d = fma(qx,cnx, fma(qy,cny, fma(qz,cnz, qw+cnw))), cn = (-2x,-2y,-2z,sq)
static __device__ __forceinline__ float distq(const float4& qp, const float4& cn) {
    return fmaf(qp.x, cn.x, fmaf(qp.y, cn.y, fmaf(qp.z, cn.z, __fadd_rn(qp.w, cn.w))));
}

// ---------------------------------------------------------------- prep + f1 (both depend only on x)
__global__ __launch_bounds__(256) void prep_f1_kernel(
    const float* __restrict__ x, float4* __restrict__ pts4, float4* __restrict__ pts4n,
    const float* __restrict__ w1, const float* __restrict__ b1,
    const float* __restrict__ w2, const float* __restrict__ b2,
    ushort* __restrict__ f1)
{
    if (blockIdx.x < 64) {
        int t = blockIdx.x * 256 + threadIdx.x;
        int b = t >> 13, n = t & (NN - 1);
        float x0 = x[(b * 3 + 0) * NN + n];
        float x1 = x[(b * 3 + 1) * NN + n];
        float x2 = x[(b * 3 + 2) * NN + n];
        float sq = fmaf(x2, x2, fmaf(x1, x1, __fmul_rn(x0, x0)));
        pts4[t]  = make_float4(x0, x1, x2, sq);
        pts4n[t] = make_float4(-2.f * x0, -2.f * x1, -2.f * x2, sq);
    } else {
        int P = (blockIdx.x - 64) * 256 + threadIdx.x;
        int b = P >> 13, n = P & (NN - 1);
        float x0 = x[(b * 3 + 0) * NN + n];
        float x1 = x[(b * 3 + 1) * NN + n];
        float x2 = x[(b * 3 + 2) * NN + n];
        float h[32];
#pragma unroll
        for (int o = 0; o < 32; ++o) {
            float v = fmaf(w1[o * 3 + 2], x2, fmaf(w1[o * 3 + 1], x1, fmaf(w1[o * 3 + 0], x0, b1[o])));
            h[o] = fmaxf(v, 0.f);
        }
#pragma unroll
        for (int o4 = 0; o4 < 16; ++o4) {
            float vv[4];
#pragma unroll
            for (int u = 0; u < 4; ++u) {
                int o = o4 * 4 + u;
                float v = b2[o];
#pragma unroll
                for (int k = 0; k < 32; ++k) v = fmaf(w2[o * 32 + k], h[k], v);
                vv[u] = fmaxf(v, 0.f);
            }
            ushort4 s = { f2bf(vv[0]), f2bf(vv[1]), f2bf(vv[2]), f2bf(vv[3]) };
            *(ushort4*)(f1 + (size_t)P * 64 + o4 * 4) = s;
        }
    }
}

// ---------------------------------------------------------------- knn K1: prefix -> conservative per-query threshold
__global__ __launch_bounds__(512) void knn_prefix_kernel(
    const float4* __restrict__ pts4, const float4* __restrict__ pts4n,
    float* __restrict__ thrb)
{
    __shared__ float smem[8 * 4 * 64];   // [wave][rank][query], 8 KB

    const int t    = threadIdx.x;
    const int wv   = t >> 6;
    const int lane = t & 63;
    const int b    = blockIdx.y;
    const int q    = blockIdx.x * QPB + lane;
    const int sl   = __builtin_amdgcn_readfirstlane(wv);

    const float4 qp = pts4[b * NN + q];
    const float4* __restrict__ cp = pts4n + (size_t)b * NN + (size_t)sl * 1024;

    float l0 = 3.0e38f, l1 = 3.0e38f, l2 = 3.0e38f, l3 = 3.0e38f;

    for (int i0 = 0; i0 < PRE; i0 += 8) {
#pragma unroll
        for (int u = 0; u < 8; ++u) {
            float d = distq(qp, cp[i0 + u]);
            if (d < l3) {
                bool b2 = d < l2, b1 = d < l1, b0 = d < l0;
                l3 = b2 ? l2 : d;
                l2 = b2 ? (b1 ? l1 : d) : l2;
                l1 = b1 ? (b0 ? l0 : d) : l1;
                l0 = b0 ? d : l0;
            }
        }
    }

    smem[(wv * 4 + 0) * 64 + lane] = l0;
    smem[(wv * 4 + 1) * 64 + lane] = l1;
    smem[(wv * 4 + 2) * 64 + lane] = l2;
    smem[(wv * 4 + 3) * 64 + lane] = l3;
    __syncthreads();

    if (t < QPB) {
        float h[8];
        int kc[8];
#pragma unroll
        for (int s = 0; s < 8; ++s) { h[s] = smem[(s * 4) * 64 + t]; kc[s] = 0; }
        float best = 3.0e38f;
        for (int o = 0; o < KK; ++o) {
            best = h[0]; int bs = 0;
#pragma unroll
            for (int s = 1; s < 8; ++s) { if (h[s] < best) { best = h[s]; bs = s; } }
#pragma unroll
            for (int s = 0; s < 8; ++s) {
                if (s == bs) {
                    kc[s]++;
                    h[s] = (kc[s] < 4) ? smem[(s * 4 + kc[s]) * 64 + t] : 3.0e38f;
                }
            }
        }
        thrb[(size_t)b * NN + blockIdx.x * QPB + t] = best;   // 16th of 32-subset
    }
}

// ---------------------------------------------------------------- knn K2: full scan vs float threshold
__global__ __launch_bounds__(512) void knn_scan_kernel(
    const float4* __restrict__ pts4, const float4* __restrict__ pts4n,
    const float* __restrict__ thrb,
    ushort* __restrict__ buf, ushort* __restrict__ cnt)
{
    const int t    = threadIdx.x;
    const int wv   = t >> 6;
    const int lane = t & 63;
    const int b    = blockIdx.y;
    const int q    = blockIdx.x * QPB + lane;          // within batch
    const int s    = __builtin_amdgcn_readfirstlane(blockIdx.z * 8 + wv);

    const float4 qp = pts4[b * NN + q];
    const float thr = thrb[(size_t)b * NN + q];
    const float4* __restrict__ cp = pts4n + (size_t)b * NN + (size_t)s * 256;
    const unsigned cbase = s * 256;

    const int cell = (((int)(b * NN) + q) << 5) + s;   // (global q)*32 + subslice
    ushort* __restrict__ bp = buf + (size_t)cell * CAP;
    int pend = 0;

    for (int i0 = 0; i0 < 256; i0 += 8) {
#pragma unroll
        for (int u = 0; u < 8; ++u) {
            const int ci = i0 + u;
            float d = distq(qp, cp[ci]);
            if (d <= thr) {
                if (pend < CAP) bp[pend] = (ushort)(cbase + ci);
                pend++;
            }
        }
    }
    cnt[cell] = (ushort)((pend < CAP) ? pend : CAP);
}

// ---------------------------------------------------------------- knn K3: exact select of survivors
__global__ __launch_bounds__(256) void knn_select_kernel(
    const float4* __restrict__ pts4, const float4* __restrict__ pts4n,
    const ushort* __restrict__ buf, const ushort* __restrict__ cnt,
    int* __restrict__ iout)
{
    __shared__ ull sm3[4][8][8][KK];   // 32 KB

    const int t = threadIdx.x;
    const int wv = t >> 6, lane = t & 63;
    const int qq = lane & 7, hh = lane >> 3;
    const int q  = (blockIdx.x * 4 + wv) * 8 + qq;     // global query 0..16383
    const int b  = q >> 13;

    const float4 qp = pts4[q];
    ull list[KK];
#pragma unroll
    for (int i = 0; i < KK; ++i) list[i] = KINF;

#pragma unroll
    for (int ss = 0; ss < 4; ++ss) {
        const int s = hh * 4 + ss;
        const int cell = (q << 5) + s;
        const int n = cnt[cell];
        const ushort* bp = buf + (size_t)cell * CAP;
        for (int i = 0; i < n; ++i) {
            int id = bp[i];
            float d = distq(qp, pts4n[b * NN + id]);
            unsigned ud = __float_as_uint(d);
            ud ^= ((unsigned)((int)ud >> 31)) | 0x80000000u;
            ull k = ((ull)ud << 32) | (unsigned)id;
#pragma unroll
            for (int i2 = KK - 1; i2 > 0; --i2) {
                bool c1 = k < list[i2];
                bool c2 = k < list[i2 - 1];
                ull nd = c2 ? list[i2 - 1] : k;
                list[i2] = c1 ? nd : list[i2];
            }
            list[0] = (k < list[0]) ? k : list[0];
        }
    }

#pragma unroll
    for (int k = 0; k < KK; ++k) sm3[wv][hh][qq][k] = list[k];

    if (hh == 0) {
        ull h[8]; int kc[8];
#pragma unroll
        for (int s = 0; s < 8; ++s) { h[s] = sm3[wv][s][qq][0]; kc[s] = 0; }
        int* op = iout + (size_t)q * KK;
        for (int o = 0; o < KK; ++o) {
            ull best = h[0]; int bs = 0;
#pragma unroll
            for (int s = 1; s < 8; ++s) { if (h[s] < best) { best = h[s]; bs = s; } }
            op[o] = (int)(unsigned)(best & 0xFFFFFFFFULL);
#pragma unroll
            for (int s = 0; s < 8; ++s) {
                if (s == bs) {
                    kc[s]++;
                    h[s] = (kc[s] < KK) ? sm3[wv][s][qq][kc[s]] : KINF;
                }
            }
        }
    }
}

// ---------------------------------------------------------------- attention (fused, weights in LDS) + cov (independent, block-split)
__global__ __launch_bounds__(256, 2) void attn_cov_kernel(
    const ushort* __restrict__ f1, const int* __restrict__ idx,
    const float* __restrict__ aw1, const float* __restrict__ ab1,
    const float* __restrict__ aw2, const float* __restrict__ ab2,
    ushort* __restrict__ fagg,
    const float4* __restrict__ pts4,
    const float* __restrict__ cw, const float* __restrict__ cb,
    ushort* __restrict__ fcov)
{
    __shared__ __align__(16) ushort w1l[128][72];      // 18.0 KB
    __shared__ __align__(16) ushort w2l[64][136];      // 17.0 KB
    __shared__ __align__(16) ushort fkb[4][16][72];    //  9.0 KB
    __shared__ __align__(16) ushort hb[4][16][136];    // 17.0 KB

    const int t = threadIdx.x;

    if (blockIdx.x >= 512) {
        // ------------------------------ cov + mlp2 (blocks 512..575)
        int P = (blockIdx.x - 512) * 256 + t;
        int b = P >> 13;
        const int4* ip4 = (const int4*)(idx + (size_t)P * KK);
        int ids[KK];
#pragma unroll
        for (int g = 0; g < 4; ++g) {
            int4 v = ip4[g];
            ids[g * 4 + 0] = v.x; ids[g * 4 + 1] = v.y;
            ids[g * 4 + 2] = v.z; ids[g * 4 + 3] = v.w;
        }
        float px[KK], py[KK], pz[KK];
#pragma unroll
        for (int k = 0; k < KK; ++k) {
            float4 c = pts4[b * NN + ids[k]];
            px[k] = c.x; py[k] = c.y; pz[k] = c.z;
        }
        float mx = 0.f, my = 0.f, mz = 0.f;
#pragma unroll
        for (int k = 0; k < KK; ++k) { mx += px[k]; my += py[k]; mz += pz[k]; }
        mx *= (1.f / 16.f); my *= (1.f / 16.f); mz *= (1.f / 16.f);
        float c00 = 0, c01 = 0, c02 = 0, c11 = 0, c12 = 0, c22 = 0;
#pragma unroll
        for (int k = 0; k < KK; ++k) {
            float dx = px[k] - mx, dy = py[k] - my, dz = pz[k] - mz;
            c00 = fmaf(dx, dx, c00); c01 = fmaf(dx, dy, c01); c02 = fmaf(dx, dz, c02);
            c11 = fmaf(dy, dy, c11); c12 = fmaf(dy, dz, c12); c22 = fmaf(dz, dz, c22);
        }
        const float inv = 1.f / 16.f;
        float cf[9] = { c00 * inv, c01 * inv, c02 * inv,
                        c01 * inv, c11 * inv, c12 * inv,
                        c02 * inv, c12 * inv, c22 * inv };
        ushort* outp = fcov + (size_t)P * 32;
#pragma unroll
        for (int o = 0; o < 32; ++o) {
            float v = cb[o];
#pragma unroll
            for (int m = 0; m < 9; ++m) v = fmaf(cw[o * 9 + m], cf[m], v);
            outp[o] = f2bf(fmaxf(v, 0.f));
        }
        return;
    }

    // ------------------------------ attention (blocks 0..511)
    const int wv = t >> 6, lane = t & 63;
    const int l15 = lane & 15, qd = lane >> 4;

    for (int i = t; i < 128 * 64; i += 256) {
        int r = i >> 6, c = i & 63;
        w1l[r][c] = f2bf(aw1[i]);
    }
    for (int i = t; i < 64 * 128; i += 256) {
        int r = i >> 7, c = i & 127;
        w2l[r][c] = f2bf(aw2[i]);
    }
    __syncthreads();

    const int W = blockIdx.x * 4 + wv;
    for (int g = 0; g < 8; ++g) {
        const int P = W * 8 + g;
        const int b = P >> 13;

        float fc = bf2f(f1[(size_t)P * 64 + lane]);
        ushort fn[15];
#pragma unroll
        for (int j = 0; j < 15; ++j) {
            int nb = idx[(size_t)P * KK + 1 + j];
            fn[j] = f1[((size_t)b * NN + nb) * 64 + lane];
        }
#pragma unroll
        for (int j = 0; j < 15; ++j) fkb[wv][j][lane] = f2bf(bf2f(fn[j]) - fc);
        fkb[wv][15][lane] = 0;

        short8 a0 = *(const short8*)&fkb[wv][l15][qd * 8];
        short8 a1 = *(const short8*)&fkb[wv][l15][32 + qd * 8];

#pragma unroll
        for (int tile = 0; tile < 8; ++tile) {
            float bv = ab1[tile * 16 + l15];
            f32x4 acc = { bv, bv, bv, bv };
            short8 b0 = *(const short8*)&w1l[tile * 16 + l15][qd * 8];
            short8 b1f = *(const short8*)&w1l[tile * 16 + l15][32 + qd * 8];
            acc = __builtin_amdgcn_mfma_f32_16x16x32_bf16(a0, b0, acc, 0, 0, 0);
            acc = __builtin_amdgcn_mfma_f32_16x16x32_bf16(a1, b1f, acc, 0, 0, 0);
#pragma unroll
            for (int reg = 0; reg < 4; ++reg)
                hb[wv][qd * 4 + reg][tile * 16 + l15] = f2bf(fmaxf(acc[reg], 0.f));
        }

        short8 a2[4];
#pragma unroll
        for (int ks = 0; ks < 4; ++ks)
            a2[ks] = *(const short8*)&hb[wv][l15][ks * 32 + qd * 8];

        f32x4 L[4];
#pragma unroll
        for (int tile = 0; tile < 4; ++tile) {
            float bv = ab2[tile * 16 + l15];
            f32x4 acc = { bv, bv, bv, bv };
#pragma unroll
            for (int ks = 0; ks < 4; ++ks) {
                short8 bf = *(const short8*)&w2l[tile * 16 + l15][ks * 32 + qd * 8];
                acc = __builtin_amdgcn_mfma_f32_16x16x32_bf16(a2[ks], bf, acc, 0, 0, 0);
            }
            L[tile] = acc;
        }

        float fa[4];
#pragma unroll
        for (int tile = 0; tile < 4; ++tile) {
            float m1 = -3.0e38f;
#pragma unroll
            for (int reg = 0; reg < 4; ++reg)
                if (qd * 4 + reg < 15) m1 = fmaxf(m1, L[tile][reg]);
            m1 = fmaxf(m1, __shfl_xor(m1, 16));
            m1 = fmaxf(m1, __shfl_xor(m1, 32));
            float e[4], ssum = 0.f;
#pragma unroll
            for (int reg = 0; reg < 4; ++reg) {
                bool valid = (qd * 4 + reg < 15);
                e[reg] = valid ? __expf(L[tile][reg] - m1) : 0.f;
                ssum += e[reg];
            }
            ssum += __shfl_xor(ssum, 16);
            ssum += __shfl_xor(ssum, 32);
            float part = 0.f;
#pragma unroll
            for (int reg = 0; reg < 4; ++reg) {
                float fkv = bf2f(fkb[wv][qd * 4 + reg][tile * 16 + l15]);
                part = fmaf(e[reg], fkv, part);
            }
            part += __shfl_xor(part, 16);
            part += __shfl_xor(part, 32);
            fa[tile] = part / ssum;
        }
        if (qd == 0) {
#pragma unroll
            for (int tile = 0; tile < 4; ++tile)
                fagg[(size_t)P * 64 + tile * 16 + l15] = f2bf(fa[tile]);
        }
    }
}

// ---------------------------------------------------------------- mlp3 + output (bf16 MFMA) — verified round 6
__global__ __launch_bounds__(256) void mlp3_kernel(
    const ushort* __restrict__ fagg, const ushort* __restrict__ fcov,
    const float* __restrict__ w1, const float* __restrict__ b1,
    const float* __restrict__ w2, const float* __restrict__ b2,
    const float* __restrict__ x, float* __restrict__ out)
{
    __shared__ __align__(16) ushort fb[4][16][104];    // 13.3 KB
    __shared__ __align__(16) ushort hb[4][16][136];    // 17.4 KB

    const int t = threadIdx.x;
    const int wv = t >> 6, lane = t & 63;
    const int l15 = lane & 15, qd = lane >> 4;

    short8 w1f[8][3];
#pragma unroll
    for (int tile = 0; tile < 8; ++tile)
#pragma unroll
        for (int ks = 0; ks < 3; ++ks) {
            const float* p = w1 + ((size_t)(tile * 16 + l15) * 96 + ks * 32 + qd * 8);
            float4 A = *(const float4*)p, B = *(const float4*)(p + 4);
            short8 f;
            f[0] = f2bf(A.x); f[1] = f2bf(A.y); f[2] = f2bf(A.z); f[3] = f2bf(A.w);
            f[4] = f2bf(B.x); f[5] = f2bf(B.y); f[6] = f2bf(B.z); f[7] = f2bf(B.w);
            w1f[tile][ks] = f;
        }
    short8 w2f[4];
#pragma unroll
    for (int ks = 0; ks < 4; ++ks) {
        short8 f = {};
        if (l15 < 12) {
            const float* p = w2 + ((size_t)l15 * 128 + ks * 32 + qd * 8);
            float4 A = *(const float4*)p, B = *(const float4*)(p + 4);
            f[0] = f2bf(A.x); f[1] = f2bf(A.y); f[2] = f2bf(A.z); f[3] = f2bf(A.w);
            f[4] = f2bf(B.x); f[5] = f2bf(B.y); f[6] = f2bf(B.z); f[7] = f2bf(B.w);
        }
        w2f[ks] = f;
    }

    const int T = blockIdx.x * 4 + wv;    // tile 0..1023

    {
        const int pt = lane >> 2, c4 = lane & 3;
        const ushort* fap = fagg + ((size_t)(T * 16 + pt) * 64 + c4 * 16);
        *(short8*)&fb[wv][pt][c4 * 16]     = *(const short8*)(fap);
        *(short8*)&fb[wv][pt][c4 * 16 + 8] = *(const short8*)(fap + 8);
        const ushort* fcp = fcov + ((size_t)(T * 16 + pt) * 32 + c4 * 8);
        *(short8*)&fb[wv][pt][64 + c4 * 8] = *(const short8*)(fcp);
    }

    short8 a[3];
#pragma unroll
    for (int ks = 0; ks < 3; ++ks)
        a[ks] = *(const short8*)&fb[wv][l15][ks * 32 + qd * 8];

#pragma unroll
    for (int tile = 0; tile < 8; ++tile) {
        float bv = b1[tile * 16 + l15];
        f32x4 acc = { bv, bv, bv, bv };
#pragma unroll
        for (int ks = 0; ks < 3; ++ks)
            acc = __builtin_amdgcn_mfma_f32_16x16x32_bf16(a[ks], w1f[tile][ks], acc, 0, 0, 0);
#pragma unroll
        for (int reg = 0; reg < 4; ++reg)
            hb[wv][qd * 4 + reg][tile * 16 + l15] = f2bf(fmaxf(acc[reg], 0.f));
    }

    short8 a2[4];
#pragma unroll
    for (int ks = 0; ks < 4; ++ks)
        a2[ks] = *(const short8*)&hb[wv][l15][ks * 32 + qd * 8];

    float bv2 = (l15 < 12) ? b2[l15] : 0.f;
    f32x4 acc = { bv2, bv2, bv2, bv2 };
#pragma unroll
    for (int ks = 0; ks < 4; ++ks)
        acc = __builtin_amdgcn_mfma_f32_16x16x32_bf16(a2[ks], w2f[ks], acc, 0, 0, 0);

    if (l15 < 12) {
        const int c = l15 >> 2, rr = l15 & 3;
#pragma unroll
        for (int reg = 0; reg < 4; ++reg) {
            int P = T * 16 + qd * 4 + reg;
            int b = P >> 13, n = P & (NN - 1);
            float xv = x[((size_t)b * 3 + c) * NN + n];
            out[(((size_t)b * 3 + c) * 4 + rr) * NN + n] = xv + 0.15f * acc[reg];
        }
    }
}

// ---------------------------------------------------------------- launch
extern "C" void kernel_launch(void* const* d_in, const int* in_sizes, int n_in,
                              void* d_out, int out_size, void* d_ws, size_t ws_size,
                              hipStream_t stream)
{
    (void)in_sizes; (void)n_in; (void)out_size; (void)ws_size;
    const float* x    = (const float*)d_in[0];
    const float* m1w1 = (const float*)d_in[1];
    const float* m1b1 = (const float*)d_in[2];
    const float* m1w2 = (const float*)d_in[3];
    const float* m1b2 = (const float*)d_in[4];
    const float* m2w1 = (const float*)d_in[5];
    const float* m2b1 = (const float*)d_in[6];
    const float* m3w1 = (const float*)d_in[7];
    const float* m3b1 = (const float*)d_in[8];
    const float* m3w2 = (const float*)d_in[9];
    const float* m3b2 = (const float*)d_in[10];
    const float* aw1  = (const float*)d_in[11];
    const float* ab1  = (const float*)d_in[12];
    const float* aw2  = (const float*)d_in[13];
    const float* ab2  = (const float*)d_in[14];
    float* out = (float*)d_out;

    char* ws = (char*)d_ws;
    float4* pts4  = (float4*)(ws + 0);            //   262144 B
    float4* pts4n = (float4*)(ws + 262144);       //   262144 B
    float*  thrb  = (float*)(ws + 524288);        //    65536 B
    int*    idxb  = (int*)  (ws + 589824);        //  1048576 B
    ushort* cntb  = (ushort*)(ws + 1638400);      //  1048576 B
    ushort* bufb  = (ushort*)(ws + 2686976);      // 10485760 B (CAP 10)
    ushort* f1b   = (ushort*)(ws + 13172736);     //  2097152 B
    ushort* fagg  = (ushort*)(ws + 15269888);     //  2097152 B
    ushort* fcov  = (ushort*)(ws + 17367040);     //  1048576 B  (end 18.4 MB)

    prep_f1_kernel<<<128, 256, 0, stream>>>(x, pts4, pts4n, m1w1, m1b1, m1w2, m1b2, f1b);
    knn_prefix_kernel<<<dim3(NN / QPB, BB), 512, 0, stream>>>(pts4, pts4n, thrb);
    knn_scan_kernel<<<dim3(NN / QPB, BB, 4), 512, 0, stream>>>(pts4, pts4n, thrb, bufb, cntb);
    knn_select_kernel<<<512, 256, 0, stream>>>(pts4, pts4n, bufb, cntb, idxb);
    attn_cov_kernel<<<576, 256, 0, stream>>>(f1b, idxb, aw1, ab1, aw2, ab2, fagg,
                                             pts4, m2w1, m2b1, fcov);
    mlp3_kernel<<<256, 256, 0, stream>>>(fagg, fcov, m3w1, m3b1, m3w2, m3b2, x, out);
}

// Round 13
// 262.810 us; speedup vs baseline: 1.6062x; 1.0235x over previous
//
#include <hip/hip_runtime.h>

#define BB 2
#define NN 8192
#define KK 16
#define QPB 64
#define PRE 256          // prefix candidates sampled per 1024-slice
#define CAP 16           // buffered survivors per (query, subslice); pow2
typedef unsigned long long ull;
typedef unsigned short ushort;
#define KINF 0xFFFFFFFFFFFFFFFFULL

typedef __attribute__((ext_vector_type(8))) short short8;
typedef __attribute__((ext_vector_type(4))) float f32x4;

static __device__ __forceinline__ ushort f2bf(float f) {
    unsigned u = __float_as_uint(f);
    unsigned r = (u + 0x7FFFu + ((u >> 16) & 1u)) >> 16;
    return (ushort)r;
}
static __device__ __forceinline__ float bf2f(ushort s) {
    return __uint_as_float(((unsigned)s) << 16);
}

// distance form used by prefix/scan/select (consistent => thr conservative):
// d = fma(qx,cnx, fma(qy,cny, fma(qz,cnz, qw+cnw))), cn = (-2x,-2y,-2z,sq)
static __device__ __forceinline__ float distq(const float4& qp, const float4& cn) {
    return fmaf(qp.x, cn.x, fmaf(qp.y, cn.y, fmaf(qp.z, cn.z, __fadd_rn(qp.w, cn.w))));
}

// ---------------------------------------------------------------- prep + f1 (both depend only on x)
__global__ __launch_bounds__(256) void prep_f1_kernel(
    const float* __restrict__ x, float4* __restrict__ pts4, float4* __restrict__ pts4n,
    const float* __restrict__ w1, const float* __restrict__ b1,
    const float* __restrict__ w2, const float* __restrict__ b2,
    ushort* __restrict__ f1)
{
    if (blockIdx.x < 64) {
        int t = blockIdx.x * 256 + threadIdx.x;
        int b = t >> 13, n = t & (NN - 1);
        float x0 = x[(b * 3 + 0) * NN + n];
        float x1 = x[(b * 3 + 1) * NN + n];
        float x2 = x[(b * 3 + 2) * NN + n];
        float sq = fmaf(x2, x2, fmaf(x1, x1, __fmul_rn(x0, x0)));
        pts4[t]  = make_float4(x0, x1, x2, sq);
        pts4n[t] = make_float4(-2.f * x0, -2.f * x1, -2.f * x2, sq);
    } else {
        int P = (blockIdx.x - 64) * 256 + threadIdx.x;
        int b = P >> 13, n = P & (NN - 1);
        float x0 = x[(b * 3 + 0) * NN + n];
        float x1 = x[(b * 3 + 1) * NN + n];
        float x2 = x[(b * 3 + 2) * NN + n];
        float h[32];
#pragma unroll
        for (int o = 0; o < 32; ++o) {
            float v = fmaf(w1[o * 3 + 2], x2, fmaf(w1[o * 3 + 1], x1, fmaf(w1[o * 3 + 0], x0, b1[o])));
            h[o] = fmaxf(v, 0.f);
        }
#pragma unroll
        for (int o4 = 0; o4 < 16; ++o4) {
            float vv[4];
#pragma unroll
            for (int u = 0; u < 4; ++u) {
                int o = o4 * 4 + u;
                float v = b2[o];
#pragma unroll
                for (int k = 0; k < 32; ++k) v = fmaf(w2[o * 32 + k], h[k], v);
                vv[u] = fmaxf(v, 0.f);
            }
            ushort4 s = { f2bf(vv[0]), f2bf(vv[1]), f2bf(vv[2]), f2bf(vv[3]) };
            *(ushort4*)(f1 + (size_t)P * 64 + o4 * 4) = s;
        }
    }
}

// ---------------------------------------------------------------- knn K1: prefix -> conservative per-query threshold
// Deferred top-4: branchless LDS push when d < stale l3 (p~0.065/lane
// steady-state); exact predicated 4-insert runs only in drains
// (wave-any pend>=4). thr is bit-identical to the direct top-4 version.
__global__ __launch_bounds__(512) void knn_prefix_kernel(
    const float4* __restrict__ pts4, const float4* __restrict__ pts4n,
    float* __restrict__ thrb)
{
    __shared__ float pbuf[11 * 512];     // 22.5 KB pending
    __shared__ float smem[8 * 4 * 64];   // 8 KB merge

    const int t    = threadIdx.x;
    const int wv   = t >> 6;
    const int lane = t & 63;
    const int b    = blockIdx.y;
    const int q    = blockIdx.x * QPB + lane;
    const int sl   = __builtin_amdgcn_readfirstlane(wv);

    const float4 qp = pts4[b * NN + q];
    const float4* __restrict__ cp = pts4n + (size_t)b * NN + (size_t)sl * 1024;

    float l0 = 3.0e38f, l1 = 3.0e38f, l2 = 3.0e38f, l3 = 3.0e38f;
    float curmax = 3.0e38f;
    int pend = 0;

    for (int i0 = 0; i0 < PRE; i0 += 8) {
#pragma unroll
        for (int u = 0; u < 8; ++u) {
            float d = distq(qp, cp[i0 + u]);
            pbuf[pend * 512 + t] = d;            // branchless push
            pend += (d < curmax) ? 1 : 0;
        }
        if (__any(pend >= 4)) {                  // drain (exact 4-insert)
            for (int j = 0; j < 11; ++j) {
                if (!__any(j < pend)) break;
                float v = pbuf[j * 512 + t];
                float k = (j < pend) ? v : 3.0e38f;
                bool b3 = k < l3, b2 = k < l2, b1 = k < l1, b0 = k < l0;
                l3 = b3 ? (b2 ? l2 : k) : l3;
                l2 = b2 ? (b1 ? l1 : k) : l2;
                l1 = b1 ? (b0 ? l0 : k) : l1;
                l0 = b0 ? k : l0;
            }
            pend = 0;
            curmax = l3;
        }
    }
    for (int j = 0; j < 11; ++j) {               // final drain
        if (!__any(j < pend)) break;
        float v = pbuf[j * 512 + t];
        float k = (j < pend) ? v : 3.0e38f;
        bool b3 = k < l3, b2 = k < l2, b1 = k < l1, b0 = k < l0;
        l3 = b3 ? (b2 ? l2 : k) : l3;
        l2 = b2 ? (b1 ? l1 : k) : l2;
        l1 = b1 ? (b0 ? l0 : k) : l1;
        l0 = b0 ? k : l0;
    }

    __syncthreads();                              // pbuf reads done
    smem[(wv * 4 + 0) * 64 + lane] = l0;
    smem[(wv * 4 + 1) * 64 + lane] = l1;
    smem[(wv * 4 + 2) * 64 + lane] = l2;
    smem[(wv * 4 + 3) * 64 + lane] = l3;
    __syncthreads();

    if (t < QPB) {
        float h[8];
        int kc[8];
#pragma unroll
        for (int s = 0; s < 8; ++s) { h[s] = smem[(s * 4) * 64 + t]; kc[s] = 0; }
        float best = 3.0e38f;
        for (int o = 0; o < KK; ++o) {
            best = h[0]; int bs = 0;
#pragma unroll
            for (int s = 1; s < 8; ++s) { if (h[s] < best) { best = h[s]; bs = s; } }
#pragma unroll
            for (int s = 0; s < 8; ++s) {
                if (s == bs) {
                    kc[s]++;
                    h[s] = (kc[s] < 4) ? smem[(s * 4 + kc[s]) * 64 + t] : 3.0e38f;
                }
            }
        }
        thrb[(size_t)b * NN + blockIdx.x * QPB + t] = best;   // 16th of 32-subset
    }
}

// ---------------------------------------------------------------- knn K2: full scan vs float threshold
__global__ __launch_bounds__(512) void knn_scan_kernel(
    const float4* __restrict__ pts4, const float4* __restrict__ pts4n,
    const float* __restrict__ thrb,
    ushort* __restrict__ buf, ushort* __restrict__ cnt)
{
    const int t    = threadIdx.x;
    const int wv   = t >> 6;
    const int lane = t & 63;
    const int b    = blockIdx.y;
    const int q    = blockIdx.x * QPB + lane;          // within batch
    const int s    = __builtin_amdgcn_readfirstlane(blockIdx.z * 8 + wv);

    const float4 qp = pts4[b * NN + q];
    const float thr = thrb[(size_t)b * NN + q];
    const float4* __restrict__ cp = pts4n + (size_t)b * NN + (size_t)s * 256;
    const unsigned cbase = s * 256;

    const int cell = (((int)(b * NN) + q) << 5) + s;   // (global q)*32 + subslice
    ushort* __restrict__ bp = buf + (size_t)cell * CAP;
    int pend = 0;

    for (int i0 = 0; i0 < 256; i0 += 8) {
#pragma unroll
        for (int u = 0; u < 8; ++u) {
            const int ci = i0 + u;
            float d = distq(qp, cp[ci]);
            if (d <= thr) {
                bp[pend & (CAP - 1)] = (ushort)(cbase + ci);
                pend++;
            }
        }
    }
    cnt[cell] = (ushort)((pend < CAP) ? pend : CAP);
}

// ---------------------------------------------------------------- knn K3: exact select of survivors
__global__ __launch_bounds__(256) void knn_select_kernel(
    const float4* __restrict__ pts4, const float4* __restrict__ pts4n,
    const ushort* __restrict__ buf, const ushort* __restrict__ cnt,
    int* __restrict__ iout)
{
    __shared__ ull sm3[4][8][8][KK];   // 32 KB

    const int t = threadIdx.x;
    const int wv = t >> 6, lane = t & 63;
    const int qq = lane & 7, hh = lane >> 3;
    const int q  = (blockIdx.x * 4 + wv) * 8 + qq;     // global query 0..16383
    const int b  = q >> 13;

    const float4 qp = pts4[q];
    ull list[KK];
#pragma unroll
    for (int i = 0; i < KK; ++i) list[i] = KINF;

#pragma unroll
    for (int ss = 0; ss < 4; ++ss) {
        const int s = hh * 4 + ss;
        const int cell = (q << 5) + s;
        const int n = cnt[cell];
        const ushort* bp = buf + (size_t)cell * CAP;
        for (int i = 0; i < n; ++i) {
            int id = bp[i];
            float d = distq(qp, pts4n[b * NN + id]);
            unsigned ud = __float_as_uint(d);
            ud ^= ((unsigned)((int)ud >> 31)) | 0x80000000u;
            ull k = ((ull)ud << 32) | (unsigned)id;
#pragma unroll
            for (int i2 = KK - 1; i2 > 0; --i2) {
                bool c1 = k < list[i2];
                bool c2 = k < list[i2 - 1];
                ull nd = c2 ? list[i2 - 1] : k;
                list[i2] = c1 ? nd : list[i2];
            }
            list[0] = (k < list[0]) ? k : list[0];
        }
    }

#pragma unroll
    for (int k = 0; k < KK; ++k) sm3[wv][hh][qq][k] = list[k];

    if (hh == 0) {
        ull h[8]; int kc[8];
#pragma unroll
        for (int s = 0; s < 8; ++s) { h[s] = sm3[wv][s][qq][0]; kc[s] = 0; }
        int* op = iout + (size_t)q * KK;
        for (int o = 0; o < KK; ++o) {
            ull best = h[0]; int bs = 0;
#pragma unroll
            for (int s = 1; s < 8; ++s) { if (h[s] < best) { best = h[s]; bs = s; } }
            op[o] = (int)(unsigned)(best & 0xFFFFFFFFULL);
#pragma unroll
            for (int s = 0; s < 8; ++s) {
                if (s == bs) {
                    kc[s]++;
                    h[s] = (kc[s] < KK) ? sm3[wv][s][qq][kc[s]] : KINF;
                }
            }
        }
    }
}

// ---------------------------------------------------------------- attention (fused, weights in LDS) + cov (independent, block-split)
__global__ __launch_bounds__(256, 2) void attn_cov_kernel(
    const ushort* __restrict__ f1, const int* __restrict__ idx,
    const float* __restrict__ aw1, const float* __restrict__ ab1,
    const float* __restrict__ aw2, const float* __restrict__ ab2,
    ushort* __restrict__ fagg,
    const float4* __restrict__ pts4,
    const float* __restrict__ cw, const float* __restrict__ cb,
    ushort* __restrict__ fcov)
{
    __shared__ __align__(16) ushort w1l[128][72];      // 18.0 KB
    __shared__ __align__(16) ushort w2l[64][136];      // 17.0 KB
    __shared__ __align__(16) ushort fkb[4][16][72];    //  9.0 KB
    __shared__ __align__(16) ushort hb[4][16][136];    // 17.0 KB

    const int t = threadIdx.x;

    if (blockIdx.x >= 512) {
        // ------------------------------ cov + mlp2 (blocks 512..575)
        int P = (blockIdx.x - 512) * 256 + t;
        int b = P >> 13;
        const int4* ip4 = (const int4*)(idx + (size_t)P * KK);
        int ids[KK];
#pragma unroll
        for (int g = 0; g < 4; ++g) {
            int4 v = ip4[g];
            ids[g * 4 + 0] = v.x; ids[g * 4 + 1] = v.y;
            ids[g * 4 + 2] = v.z; ids[g * 4 + 3] = v.w;
        }
        float px[KK], py[KK], pz[KK];
#pragma unroll
        for (int k = 0; k < KK; ++k) {
            float4 c = pts4[b * NN + ids[k]];
            px[k] = c.x; py[k] = c.y; pz[k] = c.z;
        }
        float mx = 0.f, my = 0.f, mz = 0.f;
#pragma unroll
        for (int k = 0; k < KK; ++k) { mx += px[k]; my += py[k]; mz += pz[k]; }
        mx *= (1.f / 16.f); my *= (1.f / 16.f); mz *= (1.f / 16.f);
        float c00 = 0, c01 = 0, c02 = 0, c11 = 0, c12 = 0, c22 = 0;
#pragma unroll
        for (int k = 0; k < KK; ++k) {
            float dx = px[k] - mx, dy = py[k] - my, dz = pz[k] - mz;
            c00 = fmaf(dx, dx, c00); c01 = fmaf(dx, dy, c01); c02 = fmaf(dx, dz, c02);
            c11 = fmaf(dy, dy, c11); c12 = fmaf(dy, dz, c12); c22 = fmaf(dz, dz, c22);
        }
        const float inv = 1.f / 16.f;
        float cf[9] = { c00 * inv, c01 * inv, c02 * inv,
                        c01 * inv, c11 * inv, c12 * inv,
                        c02 * inv, c12 * inv, c22 * inv };
        ushort* outp = fcov + (size_t)P * 32;
#pragma unroll
        for (int o = 0; o < 32; ++o) {
            float v = cb[o];
#pragma unroll
            for (int m = 0; m < 9; ++m) v = fmaf(cw[o * 9 + m], cf[m], v);
            outp[o] = f2bf(fmaxf(v, 0.f));
        }
        return;
    }

    // ------------------------------ attention (blocks 0..511)
    const int wv = t >> 6, lane = t & 63;
    const int l15 = lane & 15, qd = lane >> 4;

    for (int i = t; i < 128 * 64; i += 256) {
        int r = i >> 6, c = i & 63;
        w1l[r][c] = f2bf(aw1[i]);
    }
    for (int i = t; i < 64 * 128; i += 256) {
        int r = i >> 7, c = i & 127;
        w2l[r][c] = f2bf(aw2[i]);
    }
    __syncthreads();

    const int W = blockIdx.x * 4 + wv;
    for (int g = 0; g < 8; ++g) {
        const int P = W * 8 + g;
        const int b = P >> 13;

        float fc = bf2f(f1[(size_t)P * 64 + lane]);
        ushort fn[15];
#pragma unroll
        for (int j = 0; j < 15; ++j) {
            int nb = idx[(size_t)P * KK + 1 + j];
            fn[j] = f1[((size_t)b * NN + nb) * 64 + lane];
        }
#pragma unroll
        for (int j = 0; j < 15; ++j) fkb[wv][j][lane] = f2bf(bf2f(fn[j]) - fc);
        fkb[wv][15][lane] = 0;

        short8 a0 = *(const short8*)&fkb[wv][l15][qd * 8];
        short8 a1 = *(const short8*)&fkb[wv][l15][32 + qd * 8];

#pragma unroll
        for (int tile = 0; tile < 8; ++tile) {
            float bv = ab1[tile * 16 + l15];
            f32x4 acc = { bv, bv, bv, bv };
            short8 b0 = *(const short8*)&w1l[tile * 16 + l15][qd * 8];
            short8 b1f = *(const short8*)&w1l[tile * 16 + l15][32 + qd * 8];
            acc = __builtin_amdgcn_mfma_f32_16x16x32_bf16(a0, b0, acc, 0, 0, 0);
            acc = __builtin_amdgcn_mfma_f32_16x16x32_bf16(a1, b1f, acc, 0, 0, 0);
#pragma unroll
            for (int reg = 0; reg < 4; ++reg)
                hb[wv][qd * 4 + reg][tile * 16 + l15] = f2bf(fmaxf(acc[reg], 0.f));
        }

        short8 a2[4];
#pragma unroll
        for (int ks = 0; ks < 4; ++ks)
            a2[ks] = *(const short8*)&hb[wv][l15][ks * 32 + qd * 8];

        f32x4 L[4];
#pragma unroll
        for (int tile = 0; tile < 4; ++tile) {
            float bv = ab2[tile * 16 + l15];
            f32x4 acc = { bv, bv, bv, bv };
#pragma unroll
            for (int ks = 0; ks < 4; ++ks) {
                short8 bf = *(const short8*)&w2l[tile * 16 + l15][ks * 32 + qd * 8];
                acc = __builtin_amdgcn_mfma_f32_16x16x32_bf16(a2[ks], bf, acc, 0, 0, 0);
            }
            L[tile] = acc;
        }

        float fa[4];
#pragma unroll
        for (int tile = 0; tile < 4; ++tile) {
            float m1 = -3.0e38f;
#pragma unroll
            for (int reg = 0; reg < 4; ++reg)
                if (qd * 4 + reg < 15) m1 = fmaxf(m1, L[tile][reg]);
            m1 = fmaxf(m1, __shfl_xor(m1, 16));
            m1 = fmaxf(m1, __shfl_xor(m1, 32));
            float e[4], ssum = 0.f;
#pragma unroll
            for (int reg = 0; reg < 4; ++reg) {
                bool valid = (qd * 4 + reg < 15);
                e[reg] = valid ? __expf(L[tile][reg] - m1) : 0.f;
                ssum += e[reg];
            }
            ssum += __shfl_xor(ssum, 16);
            ssum += __shfl_xor(ssum, 32);
            float part = 0.f;
#pragma unroll
            for (int reg = 0; reg < 4; ++reg) {
                float fkv = bf2f(fkb[wv][qd * 4 + reg][tile * 16 + l15]);
                part = fmaf(e[reg], fkv, part);
            }
            part += __shfl_xor(part, 16);
            part += __shfl_xor(part, 32);
            fa[tile] = part / ssum;
        }
        if (qd == 0) {
#pragma unroll
            for (int tile = 0; tile < 4; ++tile)
                fagg[(size_t)P * 64 + tile * 16 + l15] = f2bf(fa[tile]);
        }
    }
}

// ---------------------------------------------------------------- mlp3 + output (bf16 MFMA) — verified round 6
__global__ __launch_bounds__(256) void mlp3_kernel(
    const ushort* __restrict__ fagg, const ushort* __restrict__ fcov,
    const float* __restrict__ w1, const float* __restrict__ b1,
    const float* __restrict__ w2, const float* __restrict__ b2,
    const float* __restrict__ x, float* __restrict__ out)
{
    __shared__ __align__(16) ushort fb[4][16][104];    // 13.3 KB
    __shared__ __align__(16) ushort hb[4][16][136];    // 17.4 KB

    const int t = threadIdx.x;
    const int wv = t >> 6, lane = t & 63;
    const int l15 = lane & 15, qd = lane >> 4;

    short8 w1f[8][3];
#pragma unroll
    for (int tile = 0; tile < 8; ++tile)
#pragma unroll
        for (int ks = 0; ks < 3; ++ks) {
            const float* p = w1 + ((size_t)(tile * 16 + l15) * 96 + ks * 32 + qd * 8);
            float4 A = *(const float4*)p, B = *(const float4*)(p + 4);
            short8 f;
            f[0] = f2bf(A.x); f[1] = f2bf(A.y); f[2] = f2bf(A.z); f[3] = f2bf(A.w);
            f[4] = f2bf(B.x); f[5] = f2bf(B.y); f[6] = f2bf(B.z); f[7] = f2bf(B.w);
            w1f[tile][ks] = f;
        }
    short8 w2f[4];
#pragma unroll
    for (int ks = 0; ks < 4; ++ks) {
        short8 f = {};
        if (l15 < 12) {
            const float* p = w2 + ((size_t)l15 * 128 + ks * 32 + qd * 8);
            float4 A = *(const float4*)p, B = *(const float4*)(p + 4);
            f[0] = f2bf(A.x); f[1] = f2bf(A.y); f[2] = f2bf(A.z); f[3] = f2bf(A.w);
            f[4] = f2bf(B.x); f[5] = f2bf(B.y); f[6] = f2bf(B.z); f[7] = f2bf(B.w);
        }
        w2f[ks] = f;
    }

    const int T = blockIdx.x * 4 + wv;    // tile 0..1023

    {
        const int pt = lane >> 2, c4 = lane & 3;
        const ushort* fap = fagg + ((size_t)(T * 16 + pt) * 64 + c4 * 16);
        *(short8*)&fb[wv][pt][c4 * 16]     = *(const short8*)(fap);
        *(short8*)&fb[wv][pt][c4 * 16 + 8] = *(const short8*)(fap + 8);
        const ushort* fcp = fcov + ((size_t)(T * 16 + pt) * 32 + c4 * 8);
        *(short8*)&fb[wv][pt][64 + c4 * 8] = *(const short8*)(fcp);
    }

    short8 a[3];
#pragma unroll
    for (int ks = 0; ks < 3; ++ks)
        a[ks] = *(const short8*)&fb[wv][l15][ks * 32 + qd * 8];

#pragma unroll
    for (int tile = 0; tile < 8; ++tile) {
        float bv = b1[tile * 16 + l15];
        f32x4 acc = { bv, bv, bv, bv };
#pragma unroll
        for (int ks = 0; ks < 3; ++ks)
            acc = __builtin_amdgcn_mfma_f32_16x16x32_bf16(a[ks], w1f[tile][ks], acc, 0, 0, 0);
#pragma unroll
        for (int reg = 0; reg < 4; ++reg)
            hb[wv][qd * 4 + reg][tile * 16 + l15] = f2bf(fmaxf(acc[reg], 0.f));
    }

    short8 a2[4];
#pragma unroll
    for (int ks = 0; ks < 4; ++ks)
        a2[ks] = *(const short8*)&hb[wv][l15][ks * 32 + qd * 8];

    float bv2 = (l15 < 12) ? b2[l15] : 0.f;
    f32x4 acc = { bv2, bv2, bv2, bv2 };
#pragma unroll
    for (int ks = 0; ks < 4; ++ks)
        acc = __builtin_amdgcn_mfma_f32_16x16x32_bf16(a2[ks], w2f[ks], acc, 0, 0, 0);

    if (l15 < 12) {
        const int c = l15 >> 2, rr = l15 & 3;
#pragma unroll
        for (int reg = 0; reg < 4; ++reg) {
            int P = T * 16 + qd * 4 + reg;
            int b = P >> 13, n = P & (NN - 1);
            float xv = x[((size_t)b * 3 + c) * NN + n];
            out[(((size_t)b * 3 + c) * 4 + rr) * NN + n] = xv + 0.15f * acc[reg];
        }
    }
}

// ---------------------------------------------------------------- launch
extern "C" void kernel_launch(void* const* d_in, const int* in_sizes, int n_in,
                              void* d_out, int out_size, void* d_ws, size_t ws_size,
                              hipStream_t stream)
{
    (void)in_sizes; (void)n_in; (void)out_size; (void)ws_size;
    const float* x    = (const float*)d_in[0];
    const float* m1w1 = (const float*)d_in[1];
    const float* m1b1 = (const float*)d_in[2];
    const float* m1w2 = (const float*)d_in[3];
    const float* m1b2 = (const float*)d_in[4];
    const float* m2w1 = (const float*)d_in[5];
    const float* m2b1 = (const float*)d_in[6];
    const float* m3w1 = (const float*)d_in[7];
    const float* m3b1 = (const float*)d_in[8];
    const float* m3w2 = (const float*)d_in[9];
    const float* m3b2 = (const float*)d_in[10];
    const float* aw1  = (const float*)d_in[11];
    const float* ab1  = (const float*)d_in[12];
    const float* aw2  = (const float*)d_in[13];
    const float* ab2  = (const float*)d_in[14];
    float* out = (float*)d_out;

    char* ws = (char*)d_ws;
    float4* pts4  = (float4*)(ws + 0);            //   262144 B
    float4* pts4n = (float4*)(ws + 262144);       //   262144 B
    float*  thrb  = (float*)(ws + 524288);        //    65536 B
    int*    idxb  = (int*)  (ws + 589824);        //  1048576 B
    ushort* cntb  = (ushort*)(ws + 1638400);      //  1048576 B
    ushort* bufb  = (ushort*)(ws + 2686976);      // 16777216 B (CAP 16)
    ushort* f1b   = (ushort*)(ws + 19464192);     //  2097152 B
    ushort* fagg  = (ushort*)(ws + 21561344);     //  2097152 B
    ushort* fcov  = (ushort*)(ws + 23658496);     //  1048576 B  (end 24.7 MB)

    prep_f1_kernel<<<128, 256, 0, stream>>>(x, pts4, pts4n, m1w1, m1b1, m1w2, m1b2, f1b);
    knn_prefix_kernel<<<dim3(NN / QPB, BB), 512, 0, stream>>>(pts4, pts4n, thrb);
    knn_scan_kernel<<<dim3(NN / QPB, BB, 4), 512, 0, stream>>>(pts4, pts4n, thrb, bufb, cntb);
    knn_select_kernel<<<512, 256, 0, stream>>>(pts4, pts4n, bufb, cntb, idxb);
    attn_cov_kernel<<<576, 256, 0, stream>>>(f1b, idxb, aw1, ab1, aw2, ab2, fagg,
                                             pts4, m2w1, m2b1, fcov);
    mlp3_kernel<<<256, 256, 0, stream>>>(fagg, fcov, m3w1, m3b1, m3w2, m3b2, x, out);
}